// Round 6
// baseline (5342.276 us; speedup 1.0000x reference)
//
#include <hip/hip_runtime.h>
#include <cstdint>
#include <cstddef>

// ---------------------------------------------------------------------------
// MambaFusion. R5 (on R4's half-batch split-bf16 MFMA structure):
// - mgemm64_k (64x64 tile, lda/ldw/ldo generalized) for x_proj / dt_proj /
//   out_proj: 2-8x more blocks for the small-GEMM latency tail.
// - dt_proj on MFMA: x_proj emits xdbl bf16 planes (stride 64); dtw K padded
//   24->32 with zero planes; fast softplus epilogue. fp32 gemm_k deleted.
// - Dir swap: dir1 first -> bm (fm region); dir0 last fuses combine
//   x = bm*(fcb + v) in its out_proj epilogue.
// - conv 2 elems/thread (float2/short2).
// Workspace: 59,130,880 floats = 236.5 MB.
// ---------------------------------------------------------------------------

constexpr int BZv = 16, SEQ = 5, NV = 1;
constexpr int C = 384, DSTATE = 16, DCONV = 4, NLAYER = 4;
constexpr int DI = 768;
constexpr int DTR = 24;
constexpr int NTOK = (NV + 2) * SEQ * 64;  // 960
constexpr int T = NTOK + 2;                // 962
constexpr int M = BZv * T;                 // 15392
constexpr int HB = 8;                      // batches per half
constexpr int MH = HB * T;                 // 7696 rows per half
constexpr int XZdim = 2 * DI;              // 1536
constexpr int ND = DTR + 2 * DSTATE;       // 56
constexpr int NDP = 64;                    // padded xdbl plane stride
constexpr int NCHUNK = 13, TC = 74;
constexpr size_t SEC_SZ = (size_t)BZv * SEQ * C * 64;

typedef __attribute__((ext_vector_type(8))) short short8;
typedef __attribute__((ext_vector_type(4))) float floatx4;

#define GLOAD_LDS16(g, l)                                        \
  __builtin_amdgcn_global_load_lds(                              \
      (const __attribute__((address_space(1))) void*)(g),        \
      (__attribute__((address_space(3))) void*)(l), 16, 0, 0)

__device__ __forceinline__ void split_bf16(float v, short& hi, short& lo) {
  unsigned u = __float_as_uint(v);
  unsigned hib = u & 0xFFFF0000u;      // truncate to bf16
  float r = v - __uint_as_float(hib);  // exact residual
  hi = (short)(hib >> 16);
  lo = (short)(__float_as_uint(r) >> 16);
}

__device__ __forceinline__ float join_bf16(short h, short l) {
  return __uint_as_float((unsigned)(unsigned short)h << 16) +
         __uint_as_float((unsigned)(unsigned short)l << 16);
}

// ------------------------------ token assembly -----------------------------
__global__ __launch_bounds__(256) void assemble_k(
    const float* __restrict__ img, const float* __restrict__ lid,
    const float* __restrict__ rad, const float* __restrict__ gps,
    const float* __restrict__ pe, float* __restrict__ x) {
  int idx = blockIdx.x * 256 + threadIdx.x;
  int c = idx % C;
  int m = idx / C;
  int b = m / T, t = m - b * T;
  float v;
  if (t < NTOK) {
    int g_ = t >> 6, p = t & 63;
    int sec = g_ / 5, s = g_ % 5;
    int band = (c < 128) ? 0 : (c < 256 ? 1 : 2);
    int which = (band + sec) % 3;
    const float* src = (which == 0) ? img : (which == 1 ? lid : rad);
    v = src[(((size_t)(b * 5 + s) * C + c) << 6) + p];
  } else {
    v = gps[((size_t)b * 2 + (t - NTOK)) * C + c];
  }
  x[idx] = v + pe[(size_t)t * C + c];
}

// -------------------- fused LN (stats + apply -> planes) -------------------
__global__ __launch_bounds__(256) void ln_fused_k(
    const float* __restrict__ x, const float* __restrict__ g,
    const float* __restrict__ b, short* __restrict__ oh,
    short* __restrict__ ol) {
  int row = blockIdx.x * 4 + (threadIdx.x >> 6);
  int lane = threadIdx.x & 63;
  const float* xr = x + (size_t)row * C;
  float v[6];
  float s = 0.f;
#pragma unroll
  for (int j = 0; j < 6; j++) {
    v[j] = xr[lane + 64 * j];
    s += v[j];
  }
#pragma unroll
  for (int o = 32; o > 0; o >>= 1) s += __shfl_xor(s, o, 64);
  float mean = s * (1.f / 384.f);
  float q = 0.f;
#pragma unroll
  for (int j = 0; j < 6; j++) {
    float d = v[j] - mean;
    q += d * d;
  }
#pragma unroll
  for (int o = 32; o > 0; o >>= 1) q += __shfl_xor(q, o, 64);
  float rstd = rsqrtf(q * (1.f / 384.f) + 1e-5f);
#pragma unroll
  for (int j = 0; j < 6; j++) {
    int c = lane + 64 * j;
    float val = (v[j] - mean) * rstd * g[c] + b[c];
    short h, l;
    split_bf16(val, h, l);
    oh[(size_t)row * C + c] = h;
    ol[(size_t)row * C + c] = l;
  }
}

// ------------------------ fp32 -> hi/lo plane casts ------------------------
__global__ __launch_bounds__(256) void cast_k(const float* __restrict__ src,
                                              int n, short* __restrict__ oh,
                                              short* __restrict__ ol) {
  int idx = blockIdx.x * 256 + threadIdx.x;
  if (idx >= n) return;
  short h, l;
  split_bf16(src[idx], h, l);
  oh[idx] = h;
  ol[idx] = l;
}

// dtw: [rows][24] -> planes [rows][32], zero-padded cols 24..31.
__global__ __launch_bounds__(256) void cast_pad_k(const float* __restrict__ src,
                                                  int n, short* __restrict__ oh,
                                                  short* __restrict__ ol) {
  int idx = blockIdx.x * 256 + threadIdx.x;
  if (idx >= n) return;
  int col = idx & 31, row = idx >> 5;
  float v = (col < DTR) ? src[row * DTR + col] : 0.f;
  short h, l;
  split_bf16(v, h, l);
  oh[idx] = h;
  ol[idx] = l;
}

// ----------------------- split-bf16 MFMA GEMM (128x128) --------------------
// out[row,n] = sum_k A[arow_off+row, k]*W[n,k] over row in [0,Mrows).
// ACT: 0 none, 1 lrelu(0.2). OSPLIT: write hi/lo planes (stride N).
template <int ACT, bool BIAS, bool FLIPA, bool OSPLIT>
__global__ __launch_bounds__(256) void mgemm_k(
    const short* __restrict__ Ah, const short* __restrict__ Al, int K,
    const short* __restrict__ Wh, const short* __restrict__ Wl, int N,
    const float* __restrict__ bias, float* __restrict__ Co, int ldc,
    short* __restrict__ Oh, short* __restrict__ Ol, int Mrows, int arow_off,
    int crow_off) {
  __shared__ __align__(16) short sAh[128 * 32];
  __shared__ __align__(16) short sAl[128 * 32];
  __shared__ __align__(16) short sBh[128 * 32];
  __shared__ __align__(16) short sBl[128 * 32];
  const int tid = threadIdx.x;
  const int wave = tid >> 6, lane = tid & 63;
  const int m0 = blockIdx.y * 128, n0 = blockIdx.x * 128;
  const int lrow = lane >> 2, lchunk = lane & 3;
  const int wm = (wave >> 1) * 64, wn = (wave & 1) * 64;
  const int frow = lane & 15, fquad = lane >> 4;

  size_t arow[2], wrow[2];
#pragma unroll
  for (int p = 0; p < 2; p++) {
    int r = p * 64 + wave * 16 + lrow;
    int lm = m0 + r;
    if (lm >= Mrows) lm = Mrows - 1;
    int g = arow_off + lm;
    if (FLIPA) {
      int bb = g / T;
      int tt = g - bb * T;
      g = bb * T + (T - 1 - tt);
    }
    arow[p] = (size_t)g * K;
    int gn = n0 + r;
    int sn = gn < N ? gn : N - 1;
    wrow[p] = (size_t)sn * K;
  }

  floatx4 acc[4][4] = {};
  for (int k0 = 0; k0 < K; k0 += 32) {
    if (k0) __syncthreads();
    const int kc = k0 + lchunk * 8;
#pragma unroll
    for (int p = 0; p < 2; p++) {
      short* lb = &sAh[(p * 64 + wave * 16) * 32];
      GLOAD_LDS16(Ah + arow[p] + kc, lb);
      lb = &sAl[(p * 64 + wave * 16) * 32];
      GLOAD_LDS16(Al + arow[p] + kc, lb);
      lb = &sBh[(p * 64 + wave * 16) * 32];
      GLOAD_LDS16(Wh + wrow[p] + kc, lb);
      lb = &sBl[(p * 64 + wave * 16) * 32];
      GLOAD_LDS16(Wl + wrow[p] + kc, lb);
    }
    __syncthreads();
    short8 ah[4], al[4], bh[4], bl[4];
#pragma unroll
    for (int i = 0; i < 4; i++) {
      int ra = (wm + i * 16 + frow) * 32 + fquad * 8;
      int rb = (wn + i * 16 + frow) * 32 + fquad * 8;
      ah[i] = *(const short8*)&sAh[ra];
      al[i] = *(const short8*)&sAl[ra];
      bh[i] = *(const short8*)&sBh[rb];
      bl[i] = *(const short8*)&sBl[rb];
    }
#pragma unroll
    for (int i = 0; i < 4; i++)
#pragma unroll
      for (int j = 0; j < 4; j++) {
        acc[i][j] = __builtin_amdgcn_mfma_f32_16x16x32_bf16(ah[i], bh[j],
                                                            acc[i][j], 0, 0, 0);
        acc[i][j] = __builtin_amdgcn_mfma_f32_16x16x32_bf16(al[i], bh[j],
                                                            acc[i][j], 0, 0, 0);
        acc[i][j] = __builtin_amdgcn_mfma_f32_16x16x32_bf16(ah[i], bl[j],
                                                            acc[i][j], 0, 0, 0);
      }
  }
#pragma unroll
  for (int i = 0; i < 4; i++) {
#pragma unroll
    for (int r = 0; r < 4; r++) {
      int gm = m0 + wm + i * 16 + fquad * 4 + r;
      if (gm >= Mrows) continue;
      int grow = crow_off + gm;
#pragma unroll
      for (int j = 0; j < 4; j++) {
        int gn = n0 + wn + j * 16 + frow;
        if (gn >= N) continue;
        float v = acc[i][j][r];
        if constexpr (BIAS) v += bias[gn];
        if constexpr (ACT == 1) v = v >= 0.f ? v : 0.2f * v;
        if constexpr (OSPLIT) {
          short h, l;
          split_bf16(v, h, l);
          Oh[(size_t)grow * N + gn] = h;
          Ol[(size_t)grow * N + gn] = l;
        } else {
          Co[(size_t)grow * ldc + gn] = v;
        }
      }
    }
  }
}

// ----------------------- split-bf16 MFMA GEMM (64x64) ----------------------
// Generalized strides: lda (A rows), ldw (W rows), ldo (OSPLIT out rows).
// ACT: 0 none, 2 fast-softplus, 4 combine x = e2*(e1 + v) (stride ldc).
template <int ACT, bool BIAS, bool OSPLIT>
__global__ __launch_bounds__(256) void mgemm64_k(
    const short* __restrict__ Ah, const short* __restrict__ Al, int lda, int K,
    const short* __restrict__ Wh, const short* __restrict__ Wl, int ldw, int N,
    const float* __restrict__ bias, float* __restrict__ Co, int ldc,
    short* __restrict__ Oh, short* __restrict__ Ol, int ldo,
    const float* __restrict__ e1, const float* __restrict__ e2, int Mrows,
    int crow_off) {
  __shared__ __align__(16) short sAh[64 * 32];
  __shared__ __align__(16) short sAl[64 * 32];
  __shared__ __align__(16) short sBh[64 * 32];
  __shared__ __align__(16) short sBl[64 * 32];
  const int tid = threadIdx.x;
  const int wave = tid >> 6, lane = tid & 63;
  const int m0 = blockIdx.y * 64, n0 = blockIdx.x * 64;
  const int srow = tid >> 2, schunk = tid & 3;  // 64 rows x 4 chunks of 16B
  const int frow = lane & 15, fquad = lane >> 4;

  int lm = m0 + srow;
  if (lm >= Mrows) lm = Mrows - 1;
  size_t aoff = (size_t)lm * lda;
  int wn_ = n0 + srow;
  if (wn_ >= N) wn_ = N - 1;
  size_t woff = (size_t)wn_ * ldw;

  floatx4 acc[4] = {};
  for (int k0 = 0; k0 < K; k0 += 32) {
    if (k0) __syncthreads();
    const int kc = k0 + schunk * 8;
    {
      short* lb = &sAh[(wave * 16) * 32];
      GLOAD_LDS16(Ah + aoff + kc, lb);
      lb = &sAl[(wave * 16) * 32];
      GLOAD_LDS16(Al + aoff + kc, lb);
      lb = &sBh[(wave * 16) * 32];
      GLOAD_LDS16(Wh + woff + kc, lb);
      lb = &sBl[(wave * 16) * 32];
      GLOAD_LDS16(Wl + woff + kc, lb);
    }
    __syncthreads();
    short8 ah[4], al[4], bh, bl;
#pragma unroll
    for (int i = 0; i < 4; i++) {
      int ra = (i * 16 + frow) * 32 + fquad * 8;
      ah[i] = *(const short8*)&sAh[ra];
      al[i] = *(const short8*)&sAl[ra];
    }
    {
      int rb = (wave * 16 + frow) * 32 + fquad * 8;
      bh = *(const short8*)&sBh[rb];
      bl = *(const short8*)&sBl[rb];
    }
#pragma unroll
    for (int i = 0; i < 4; i++) {
      acc[i] = __builtin_amdgcn_mfma_f32_16x16x32_bf16(ah[i], bh, acc[i], 0, 0, 0);
      acc[i] = __builtin_amdgcn_mfma_f32_16x16x32_bf16(al[i], bh, acc[i], 0, 0, 0);
      acc[i] = __builtin_amdgcn_mfma_f32_16x16x32_bf16(ah[i], bl, acc[i], 0, 0, 0);
    }
  }
  const int gn = n0 + wave * 16 + frow;
  if (gn < N) {
#pragma unroll
    for (int i = 0; i < 4; i++) {
#pragma unroll
      for (int r = 0; r < 4; r++) {
        int gm = m0 + i * 16 + fquad * 4 + r;
        if (gm >= Mrows) continue;
        int grow = crow_off + gm;
        float v = acc[i][r];
        if constexpr (BIAS) v += bias[gn];
        if constexpr (ACT == 2)
          v = (v > 20.f) ? v : __logf(1.f + __expf(v));
        if constexpr (ACT == 4) {
          size_t o = (size_t)grow * ldc + gn;
          v = e2[o] * (e1[o] + v);
        }
        if constexpr (OSPLIT) {
          short h, l;
          split_bf16(v, h, l);
          Oh[(size_t)grow * ldo + gn] = h;
          Ol[(size_t)grow * ldo + gn] = l;
        } else {
          Co[(size_t)grow * ldc + gn] = v;
        }
      }
    }
  }
}

// --------------------------- depthwise conv + silu -------------------------
// 2 elements/thread; emits xc bf16 hi/lo planes.
__global__ __launch_bounds__(256) void conv_k(const float* __restrict__ xz,
                                              const float* __restrict__ cw,
                                              const float* __restrict__ cb,
                                              short* __restrict__ xch,
                                              short* __restrict__ xcl) {
  int idx = blockIdx.x * 256 + threadIdx.x;  // [0, MH*DI/2)
  int dh = idx % (DI / 2);
  int m = idx / (DI / 2);
  int d = dh * 2;
  int b = m / T, t = m - b * T;
  const float* base = xz + (size_t)b * T * XZdim + d;
  float a0 = cb[d], a1 = cb[d + 1];
#pragma unroll
  for (int j = 0; j < 4; j++) {
    int tt = t - 3 + j;
    if (tt >= 0) {
      float2 u = *(const float2*)(base + (size_t)tt * XZdim);
      a0 += u.x * cw[d * 4 + j];
      a1 += u.y * cw[(d + 1) * 4 + j];
    }
  }
  float v0 = a0 / (1.f + __expf(-a0));
  float v1 = a1 / (1.f + __expf(-a1));
  short h0, l0, h1, l1;
  split_bf16(v0, h0, l0);
  split_bf16(v1, h1, l1);
  size_t o = (size_t)m * DI + d;
  *(short2*)&xch[o] = make_short2(h0, h1);
  *(short2*)&xcl[o] = make_short2(l0, l1);
}

// ----------------------- chunked selective scan ----------------------------
// B/C read from xdbl planes (row stride 64; B at DTR+s, C at DTR+16+s).
__global__ __launch_bounds__(256) void scan_p1_k(
    const float* __restrict__ xzb, const short* __restrict__ xch,
    const short* __restrict__ xcl, const short* __restrict__ xdh,
    const short* __restrict__ xdl, const float* __restrict__ alog,
    float* __restrict__ hchk, float* __restrict__ pchk) {
  int d = blockIdx.x * 256 + threadIdx.x;
  int ch = blockIdx.y, b = blockIdx.z;
  float A[DSTATE], h[DSTATE];
#pragma unroll
  for (int s = 0; s < DSTATE; s++) {
    A[s] = -expf(alog[d * DSTATE + s]);
    h[s] = 0.f;
  }
  const int t0 = ch * TC;
  const float* xzr = xzb + ((size_t)b * T + t0) * XZdim;
  const short* xchr = xch + ((size_t)b * T + t0) * DI;
  const short* xclr = xcl + ((size_t)b * T + t0) * DI;
  const short* xdhr = xdh + ((size_t)b * T + t0) * NDP + DTR;
  const short* xdlr = xdl + ((size_t)b * T + t0) * NDP + DTR;
  float sdt = 0.f;
  for (int t = 0; t < TC; t++) {
    float dt = xzr[(size_t)t * XZdim + d];
    float xv = join_bf16(xchr[(size_t)t * DI + d], xclr[(size_t)t * DI + d]);
    float dx = dt * xv;
    const short* bh = xdhr + (size_t)t * NDP;
    const short* bl = xdlr + (size_t)t * NDP;
    sdt += dt;
#pragma unroll
    for (int s = 0; s < DSTATE; s++) {
      float e = __expf(dt * A[s]);
      h[s] = h[s] * e + dx * join_bf16(bh[s], bl[s]);
    }
  }
  size_t o = ((size_t)(b * NCHUNK + ch) * DSTATE) * DI + d;
#pragma unroll
  for (int s = 0; s < DSTATE; s++) {
    hchk[o + (size_t)s * DI] = h[s];
    pchk[o + (size_t)s * DI] = __expf(A[s] * sdt);
  }
}

// Chunk-state propagation, parallel over (b,s,d).
__global__ __launch_bounds__(256) void scan_p2_k(float* __restrict__ hchk,
                                                 const float* __restrict__ pchk) {
  int idx = blockIdx.x * 256 + threadIdx.x;  // [0, HB*DSTATE*DI)
  int d = idx % DI;
  int rem = idx / DI;
  int s = rem % DSTATE, b = rem / DSTATE;
  float hin = 0.f;
#pragma unroll
  for (int ch = 0; ch < NCHUNK; ch++) {
    size_t o = ((size_t)(b * NCHUNK + ch) * DSTATE + s) * DI + d;
    float P = pchk[o];
    float hl = hchk[o];
    hchk[o] = hin;
    hin = P * hin + hl;
  }
}

// Phase 3: rescan from incoming state; y = h.C + D*x, gated silu(z) -> planes.
__global__ __launch_bounds__(256) void scan_p3_k(
    const float* __restrict__ xzb, const short* __restrict__ xch,
    const short* __restrict__ xcl, const short* __restrict__ xdh,
    const short* __restrict__ xdl, const float* __restrict__ alog,
    const float* __restrict__ Dp, const float* __restrict__ hchk,
    short* __restrict__ yh, short* __restrict__ yl) {
  int d = blockIdx.x * 256 + threadIdx.x;
  int ch = blockIdx.y, b = blockIdx.z;
  float A[DSTATE], h[DSTATE];
  size_t o = ((size_t)(b * NCHUNK + ch) * DSTATE) * DI + d;
#pragma unroll
  for (int s = 0; s < DSTATE; s++) {
    A[s] = -expf(alog[d * DSTATE + s]);
    h[s] = hchk[o + (size_t)s * DI];
  }
  float Dd = Dp[d];
  const int t0 = ch * TC;
  const float* xzr = xzb + ((size_t)b * T + t0) * XZdim;
  const short* xchr = xch + ((size_t)b * T + t0) * DI;
  const short* xclr = xcl + ((size_t)b * T + t0) * DI;
  const short* xdhr = xdh + ((size_t)b * T + t0) * NDP + DTR;
  const short* xdlr = xdl + ((size_t)b * T + t0) * NDP + DTR;
  for (int t = 0; t < TC; t++) {
    float dt = xzr[(size_t)t * XZdim + d];
    float xv = join_bf16(xchr[(size_t)t * DI + d], xclr[(size_t)t * DI + d]);
    float zv = xzr[(size_t)t * XZdim + DI + d];
    float dx = dt * xv;
    float accv = 0.f;
    const short* bh = xdhr + (size_t)t * NDP;
    const short* bl = xdlr + (size_t)t * NDP;
#pragma unroll
    for (int s = 0; s < DSTATE; s++) {
      float e = __expf(dt * A[s]);
      h[s] = h[s] * e + dx * join_bf16(bh[s], bl[s]);
      accv += h[s] * join_bf16(bh[DSTATE + s], bl[DSTATE + s]);
    }
    float y = accv + Dd * xv;
    float sz = zv / (1.f + __expf(-zv));
    float v = y * sz;
    short hh, ll;
    split_bf16(v, hh, ll);
    size_t oi = ((size_t)(b * T + t0 + t)) * DI + d;
    yh[oi] = hh;
    yl[oi] = ll;
  }
}

// --------------------------- final LN + scatter ----------------------------
__device__ __forceinline__ size_t out_index(int b, int t, int c) {
  if (t < NTOK) {
    int g_ = t >> 6, p = t & 63;
    int sec = g_ / 5, s = g_ % 5;
    return (size_t)sec * SEC_SZ + (((size_t)(b * 5 + s) * C + c) << 6) + p;
  }
  return 3 * SEC_SZ + ((size_t)b * 2 + (t - NTOK)) * C + c;
}

__global__ __launch_bounds__(128) void ln_scatter_k(const float* __restrict__ x,
                                                    const float* __restrict__ g,
                                                    const float* __restrict__ bb,
                                                    float* __restrict__ out) {
  int m = blockIdx.x, tid = threadIdx.x;
  int b = m / T, t = m - b * T;
  const float* xr = x + (size_t)m * C;
  float v0 = xr[tid], v1 = xr[tid + 128], v2 = xr[tid + 256];
  __shared__ float sm2[2];
  int wid = tid >> 6, lane = tid & 63;
  float s = v0 + v1 + v2;
#pragma unroll
  for (int o = 32; o > 0; o >>= 1) s += __shfl_xor(s, o, 64);
  if (lane == 0) sm2[wid] = s;
  __syncthreads();
  float mean = (sm2[0] + sm2[1]) * (1.f / 384.f);
  __syncthreads();
  float d0 = v0 - mean, d1 = v1 - mean, d2 = v2 - mean;
  float q = d0 * d0 + d1 * d1 + d2 * d2;
#pragma unroll
  for (int o = 32; o > 0; o >>= 1) q += __shfl_xor(q, o, 64);
  if (lane == 0) sm2[wid] = q;
  __syncthreads();
  float rstd = rsqrtf((sm2[0] + sm2[1]) * (1.f / 384.f) + 1e-5f);
  float vv[3] = {v0, v1, v2};
#pragma unroll
  for (int j = 0; j < 3; j++) {
    int c = tid + j * 128;
    out[out_index(b, t, c)] = (vv[j] - mean) * rstd * g[c] + bb[c];
  }
}

// --------------------------------- launch ----------------------------------
extern "C" void kernel_launch(void* const* d_in, const int* in_sizes, int n_in,
                              void* d_out, int out_size, void* d_ws,
                              size_t ws_size, hipStream_t stream) {
  const float* image = (const float*)d_in[0];
  const float* lidar = (const float*)d_in[1];
  const float* radar = (const float*)d_in[2];
  const float* gps = (const float*)d_in[3];
  const float* pe = (const float*)d_in[4];
  const float* ln1g = (const float*)d_in[5];
  const float* ln1b = (const float*)d_in[6];
  const float* fc1w = (const float*)d_in[7];
  const float* fc1b = (const float*)d_in[8];
  const float* fc2w = (const float*)d_in[9];
  const float* fc2b_ = (const float*)d_in[10];
  const float* inw = (const float*)d_in[11];
  const float* cw = (const float*)d_in[12];
  const float* cb = (const float*)d_in[13];
  const float* xw = (const float*)d_in[14];
  const float* dtw = (const float*)d_in[15];
  const float* dtb = (const float*)d_in[16];
  const float* alog = (const float*)d_in[17];
  const float* Dp = (const float*)d_in[18];
  const float* ow = (const float*)d_in[19];
  const float* lnfg = (const float*)d_in[20];
  const float* lnfb = (const float*)d_in[21];
  float* out = (float*)d_out;

  // ---------------- workspace carve-up (59,130,880 floats = 236.5 MB) ------
  constexpr size_t MC = (size_t)M * C;  // 5,910,528
  float* ws = (float*)d_ws;
  float* x = ws;                            // MC
  float* fcb = x + MC;                      // MC (fc2 lrelu result)
  float* bmfm = fcb + MC;                   // MC (ln planes alias; then bm)
  float* x1f = bmfm + MC;                   // MC (x1 planes)
  float* yf = x1f + MC;                     // MC (y planes, half-local)
  float* xz_h = yf + MC;                    // MH*1536
  float* xcp = xz_h + (size_t)MH * XZdim;   // MH*DI floats (xc planes)
  float* xdp = xcp + (size_t)MH * DI;       // MH*64 floats (xdbl planes)
  constexpr size_t CHK_H = (size_t)HB * NCHUNK * DSTATE * DI;  // 1,277,952
  float* hchk = xdp + (size_t)MH * NDP / 2 * 2;  // = xdp + MH*64
  float* pchk = hchk + CHK_H;
  float* wpl = pchk + CHK_H;

  short* lnh = (short*)bmfm;  // ln planes dead before bm written
  short* lnl = lnh + MC;
  float* bm = bmfm;  // dir1 out_proj result (fp32, full M)
  short* x1h = (short*)x1f;
  short* x1l = x1h + MC;
  short* yh = (short*)yf;
  short* yl = yh + (size_t)MH * DI;
  short* xch = (short*)xcp;
  short* xcl = xch + (size_t)MH * DI;
  short* xdh = (short*)xdp;
  short* xdl = xdh + (size_t)MH * NDP;

  constexpr size_t WSZ1 = (size_t)NLAYER * C * C;           // 589,824
  constexpr size_t WSZI = (size_t)NLAYER * 2 * 2 * DI * C;  // 4,718,592
  constexpr size_t WSZO = (size_t)NLAYER * 2 * C * DI;      // 2,359,296
  constexpr size_t WSZX = (size_t)NLAYER * 2 * ND * DI;     // 344,064
  constexpr size_t WSZD = (size_t)NLAYER * 2 * DI * 32;     // 196,608 (padded)
  short* wf1h = (short*)wpl;
  short* wf1l = wf1h + WSZ1;
  short* wf2h = wf1l + WSZ1;
  short* wf2l = wf2h + WSZ1;
  short* winh = wf2l + WSZ1;
  short* winl = winh + WSZI;
  short* wowh = winl + WSZI;
  short* wowl = wowh + WSZO;
  short* wxh = wowl + WSZO;
  short* wxl = wxh + WSZX;
  short* wdth = wxl + WSZX;
  short* wdtl = wdth + WSZD;

  // ---------------- weight plane casts (once per call) ----------------
  cast_k<<<(int)(WSZ1 / 256), 256, 0, stream>>>(fc1w, (int)WSZ1, wf1h, wf1l);
  cast_k<<<(int)(WSZ1 / 256), 256, 0, stream>>>(fc2w, (int)WSZ1, wf2h, wf2l);
  cast_k<<<(int)(WSZI / 256), 256, 0, stream>>>(inw, (int)WSZI, winh, winl);
  cast_k<<<(int)(WSZO / 256), 256, 0, stream>>>(ow, (int)WSZO, wowh, wowl);
  cast_k<<<(int)(WSZX / 256), 256, 0, stream>>>(xw, (int)WSZX, wxh, wxl);
  cast_pad_k<<<(int)(WSZD / 256), 256, 0, stream>>>(dtw, (int)WSZD, wdth, wdtl);

  assemble_k<<<(M * C) / 256, 256, 0, stream>>>(image, lidar, radar, gps, pe, x);

  for (int l = 0; l < NLAYER; l++) {
    ln_fused_k<<<M / 4, 256, 0, stream>>>(x, ln1g + l * C, ln1b + l * C, lnh,
                                          lnl);
    // fc1 = LN(x) @ fc1_w^T + b -> bf16 planes (full M)
    mgemm_k<0, true, false, true><<<dim3(3, 121), 256, 0, stream>>>(
        lnh, lnl, C, wf1h + (size_t)l * C * C, wf1l + (size_t)l * C * C, C,
        fc1b + l * C, nullptr, 0, x1h, x1l, M, 0, 0);
    // fcb = lrelu(flip(xfc1) @ fc2_w^T + b) -> fp32 (full M)
    mgemm_k<1, true, true, false><<<dim3(3, 121), 256, 0, stream>>>(
        x1h, x1l, C, wf2h + (size_t)l * C * C, wf2l + (size_t)l * C * C, C,
        fc2b_ + l * C, fcb, C, nullptr, nullptr, M, 0, 0);
    // dir1 (backward) first -> bm; dir0 last fuses combine into x.
    for (int di = 0; di < 2; di++) {
      const int dir = 1 - di;
      size_t wo = (size_t)(l * 2 + dir);
      for (int h = 0; h < 2; h++) {
        const int roff = h * MH;
        // in_proj -> xz_h (dir1 reads time-flipped rows of x1)
        if (dir == 0)
          mgemm_k<0, false, false, false><<<dim3(12, 61), 256, 0, stream>>>(
              x1h, x1l, C, winh + wo * 2 * DI * C, winl + wo * 2 * DI * C,
              2 * DI, nullptr, xz_h, XZdim, nullptr, nullptr, MH, roff, 0);
        else
          mgemm_k<0, false, true, false><<<dim3(12, 61), 256, 0, stream>>>(
              x1h, x1l, C, winh + wo * 2 * DI * C, winl + wo * 2 * DI * C,
              2 * DI, nullptr, xz_h, XZdim, nullptr, nullptr, MH, roff, 0);
        // causal depthwise conv + silu -> xc planes
        conv_k<<<(MH * DI / 2) / 256, 256, 0, stream>>>(
            xz_h, cw + wo * DI * DCONV, cb + wo * DI, xch, xcl);
        // x_proj -> xdbl planes (N=56, ldo=64)
        mgemm64_k<0, false, true><<<dim3(1, 121), 256, 0, stream>>>(
            xch, xcl, DI, DI, wxh + wo * ND * DI, wxl + wo * ND * DI, DI, ND,
            nullptr, nullptr, 0, xdh, xdl, NDP, nullptr, nullptr, MH, 0);
        // dt_proj (K padded 24->32, zero weight pad) + fast softplus -> xz dt
        mgemm64_k<2, true, false><<<dim3(12, 121), 256, 0, stream>>>(
            xdh, xdl, NDP, 32, wdth + wo * DI * 32, wdtl + wo * DI * 32, 32,
            DI, dtb + wo * DI, xz_h, XZdim, nullptr, nullptr, 0, nullptr,
            nullptr, MH, 0);
        // chunked selective scan -> y planes
        scan_p1_k<<<dim3(3, NCHUNK, HB), 256, 0, stream>>>(
            xz_h, xch, xcl, xdh, xdl, alog + wo * DI * DSTATE, hchk, pchk);
        scan_p2_k<<<(HB * DSTATE * DI) / 256, 256, 0, stream>>>(hchk, pchk);
        scan_p3_k<<<dim3(3, NCHUNK, HB), 256, 0, stream>>>(
            xz_h, xch, xcl, xdh, xdl, alog + wo * DI * DSTATE, Dp + wo * DI,
            hchk, yh, yl);
        // out_proj: dir1 -> bm (plain); dir0 -> x = bm*(fcb + v)
        if (dir == 1)
          mgemm64_k<0, false, false><<<dim3(6, 121), 256, 0, stream>>>(
              yh, yl, DI, DI, wowh + wo * C * DI, wowl + wo * C * DI, DI, C,
              nullptr, bm, C, nullptr, nullptr, 0, nullptr, nullptr, MH, roff);
        else
          mgemm64_k<4, false, false><<<dim3(6, 121), 256, 0, stream>>>(
              yh, yl, DI, DI, wowh + wo * C * DI, wowl + wo * C * DI, DI, C,
              nullptr, x, C, nullptr, nullptr, 0, fcb, bm, MH, roff);
      }
    }
  }
  ln_scatter_k<<<M, 128, 0, stream>>>(x, lnfg, lnfb, out);
}

// Round 8
// 3720.714 us; speedup vs baseline: 1.4358x; 1.4358x over previous
//
#include <hip/hip_runtime.h>
#include <cstdint>
#include <cstddef>

// ---------------------------------------------------------------------------
// MambaFusion. R7 = R6 with the xdp aliasing fix (xdbc was overlapping xdl,
// NaN). Layout of xdp region (MH*64 floats): dt_r hi plane [0,16MH) floats,
// lo plane [16MH,32MH), fp32 B|C [32MH,64MH).
// R6 content: NCHUNK 26 (TC=37) scan, sum(dt)-based p2 (pchk deleted),
// exp via pow16 chain when A[s]~=-(s+1) (runtime-checked), B/C fp32.
// Workspace: 59,290,624 floats = 237.2 MB.
// ---------------------------------------------------------------------------

constexpr int BZv = 16, SEQ = 5, NV = 1;
constexpr int C = 384, DSTATE = 16, DCONV = 4, NLAYER = 4;
constexpr int DI = 768;
constexpr int DTR = 24;
constexpr int NTOK = (NV + 2) * SEQ * 64;  // 960
constexpr int T = NTOK + 2;                // 962
constexpr int M = BZv * T;                 // 15392
constexpr int HB = 8;                      // batches per half
constexpr int MH = HB * T;                 // 7696 rows per half
constexpr int XZdim = 2 * DI;              // 1536
constexpr int ND = DTR + 2 * DSTATE;       // 56
constexpr int NDP = 32;                    // dt_r plane stride
constexpr int NCHUNK = 26, TC = 37;        // 26*37 == 962
constexpr size_t SEC_SZ = (size_t)BZv * SEQ * C * 64;

typedef __attribute__((ext_vector_type(8))) short short8;
typedef __attribute__((ext_vector_type(4))) float floatx4;

#define GLOAD_LDS16(g, l)                                        \
  __builtin_amdgcn_global_load_lds(                              \
      (const __attribute__((address_space(1))) void*)(g),        \
      (__attribute__((address_space(3))) void*)(l), 16, 0, 0)

__device__ __forceinline__ void split_bf16(float v, short& hi, short& lo) {
  unsigned u = __float_as_uint(v);
  unsigned hib = u & 0xFFFF0000u;      // truncate to bf16
  float r = v - __uint_as_float(hib);  // exact residual
  hi = (short)(hib >> 16);
  lo = (short)(__float_as_uint(r) >> 16);
}

__device__ __forceinline__ float join_bf16(short h, short l) {
  return __uint_as_float((unsigned)(unsigned short)h << 16) +
         __uint_as_float((unsigned)(unsigned short)l << 16);
}

// e[s] = e1^(s+1), 15 muls, ~4 deep.
__device__ __forceinline__ void pow16(float e1, float* e) {
  e[0] = e1;
  e[1] = e1 * e1;
  e[3] = e[1] * e[1];
  e[7] = e[3] * e[3];
  e[15] = e[7] * e[7];
  e[2] = e[1] * e[0];
  e[4] = e[3] * e[0];
  e[5] = e[3] * e[1];
  e[6] = e[5] * e[0];
  e[8] = e[7] * e[0];
  e[9] = e[7] * e[1];
  e[10] = e[9] * e[0];
  e[11] = e[7] * e[3];
  e[12] = e[11] * e[0];
  e[13] = e[11] * e[1];
  e[14] = e[13] * e[0];
}

// ------------------------------ token assembly -----------------------------
__global__ __launch_bounds__(256) void assemble_k(
    const float* __restrict__ img, const float* __restrict__ lid,
    const float* __restrict__ rad, const float* __restrict__ gps,
    const float* __restrict__ pe, float* __restrict__ x) {
  int idx = blockIdx.x * 256 + threadIdx.x;
  int c = idx % C;
  int m = idx / C;
  int b = m / T, t = m - b * T;
  float v;
  if (t < NTOK) {
    int g_ = t >> 6, p = t & 63;
    int sec = g_ / 5, s = g_ % 5;
    int band = (c < 128) ? 0 : (c < 256 ? 1 : 2);
    int which = (band + sec) % 3;
    const float* src = (which == 0) ? img : (which == 1 ? lid : rad);
    v = src[(((size_t)(b * 5 + s) * C + c) << 6) + p];
  } else {
    v = gps[((size_t)b * 2 + (t - NTOK)) * C + c];
  }
  x[idx] = v + pe[(size_t)t * C + c];
}

// -------------------- fused LN (stats + apply -> planes) -------------------
__global__ __launch_bounds__(256) void ln_fused_k(
    const float* __restrict__ x, const float* __restrict__ g,
    const float* __restrict__ b, short* __restrict__ oh,
    short* __restrict__ ol) {
  int row = blockIdx.x * 4 + (threadIdx.x >> 6);
  int lane = threadIdx.x & 63;
  const float* xr = x + (size_t)row * C;
  float v[6];
  float s = 0.f;
#pragma unroll
  for (int j = 0; j < 6; j++) {
    v[j] = xr[lane + 64 * j];
    s += v[j];
  }
#pragma unroll
  for (int o = 32; o > 0; o >>= 1) s += __shfl_xor(s, o, 64);
  float mean = s * (1.f / 384.f);
  float q = 0.f;
#pragma unroll
  for (int j = 0; j < 6; j++) {
    float d = v[j] - mean;
    q += d * d;
  }
#pragma unroll
  for (int o = 32; o > 0; o >>= 1) q += __shfl_xor(q, o, 64);
  float rstd = rsqrtf(q * (1.f / 384.f) + 1e-5f);
#pragma unroll
  for (int j = 0; j < 6; j++) {
    int c = lane + 64 * j;
    float val = (v[j] - mean) * rstd * g[c] + b[c];
    short h, l;
    split_bf16(val, h, l);
    oh[(size_t)row * C + c] = h;
    ol[(size_t)row * C + c] = l;
  }
}

// ------------------------ fp32 -> hi/lo plane casts ------------------------
__global__ __launch_bounds__(256) void cast_k(const float* __restrict__ src,
                                              int n, short* __restrict__ oh,
                                              short* __restrict__ ol) {
  int idx = blockIdx.x * 256 + threadIdx.x;
  if (idx >= n) return;
  short h, l;
  split_bf16(src[idx], h, l);
  oh[idx] = h;
  ol[idx] = l;
}

// dtw: [rows][24] -> planes [rows][32], zero-padded cols 24..31.
__global__ __launch_bounds__(256) void cast_pad_k(const float* __restrict__ src,
                                                  int n, short* __restrict__ oh,
                                                  short* __restrict__ ol) {
  int idx = blockIdx.x * 256 + threadIdx.x;
  if (idx >= n) return;
  int col = idx & 31, row = idx >> 5;
  float v = (col < DTR) ? src[row * DTR + col] : 0.f;
  short h, l;
  split_bf16(v, h, l);
  oh[idx] = h;
  ol[idx] = l;
}

// ----------------------- split-bf16 MFMA GEMM (128x128) --------------------
// ACT: 0 none, 1 lrelu(0.2). OSPLIT: write hi/lo planes (stride N).
template <int ACT, bool BIAS, bool FLIPA, bool OSPLIT>
__global__ __launch_bounds__(256) void mgemm_k(
    const short* __restrict__ Ah, const short* __restrict__ Al, int K,
    const short* __restrict__ Wh, const short* __restrict__ Wl, int N,
    const float* __restrict__ bias, float* __restrict__ Co, int ldc,
    short* __restrict__ Oh, short* __restrict__ Ol, int Mrows, int arow_off,
    int crow_off) {
  __shared__ __align__(16) short sAh[128 * 32];
  __shared__ __align__(16) short sAl[128 * 32];
  __shared__ __align__(16) short sBh[128 * 32];
  __shared__ __align__(16) short sBl[128 * 32];
  const int tid = threadIdx.x;
  const int wave = tid >> 6, lane = tid & 63;
  const int m0 = blockIdx.y * 128, n0 = blockIdx.x * 128;
  const int lrow = lane >> 2, lchunk = lane & 3;
  const int wm = (wave >> 1) * 64, wn = (wave & 1) * 64;
  const int frow = lane & 15, fquad = lane >> 4;

  size_t arow[2], wrow[2];
#pragma unroll
  for (int p = 0; p < 2; p++) {
    int r = p * 64 + wave * 16 + lrow;
    int lm = m0 + r;
    if (lm >= Mrows) lm = Mrows - 1;
    int g = arow_off + lm;
    if (FLIPA) {
      int bb = g / T;
      int tt = g - bb * T;
      g = bb * T + (T - 1 - tt);
    }
    arow[p] = (size_t)g * K;
    int gn = n0 + r;
    int sn = gn < N ? gn : N - 1;
    wrow[p] = (size_t)sn * K;
  }

  floatx4 acc[4][4] = {};
  for (int k0 = 0; k0 < K; k0 += 32) {
    if (k0) __syncthreads();
    const int kc = k0 + lchunk * 8;
#pragma unroll
    for (int p = 0; p < 2; p++) {
      short* lb = &sAh[(p * 64 + wave * 16) * 32];
      GLOAD_LDS16(Ah + arow[p] + kc, lb);
      lb = &sAl[(p * 64 + wave * 16) * 32];
      GLOAD_LDS16(Al + arow[p] + kc, lb);
      lb = &sBh[(p * 64 + wave * 16) * 32];
      GLOAD_LDS16(Wh + wrow[p] + kc, lb);
      lb = &sBl[(p * 64 + wave * 16) * 32];
      GLOAD_LDS16(Wl + wrow[p] + kc, lb);
    }
    __syncthreads();
    short8 ah[4], al[4], bh[4], bl[4];
#pragma unroll
    for (int i = 0; i < 4; i++) {
      int ra = (wm + i * 16 + frow) * 32 + fquad * 8;
      int rb = (wn + i * 16 + frow) * 32 + fquad * 8;
      ah[i] = *(const short8*)&sAh[ra];
      al[i] = *(const short8*)&sAl[ra];
      bh[i] = *(const short8*)&sBh[rb];
      bl[i] = *(const short8*)&sBl[rb];
    }
#pragma unroll
    for (int i = 0; i < 4; i++)
#pragma unroll
      for (int j = 0; j < 4; j++) {
        acc[i][j] = __builtin_amdgcn_mfma_f32_16x16x32_bf16(ah[i], bh[j],
                                                            acc[i][j], 0, 0, 0);
        acc[i][j] = __builtin_amdgcn_mfma_f32_16x16x32_bf16(al[i], bh[j],
                                                            acc[i][j], 0, 0, 0);
        acc[i][j] = __builtin_amdgcn_mfma_f32_16x16x32_bf16(ah[i], bl[j],
                                                            acc[i][j], 0, 0, 0);
      }
  }
#pragma unroll
  for (int i = 0; i < 4; i++) {
#pragma unroll
    for (int r = 0; r < 4; r++) {
      int gm = m0 + wm + i * 16 + fquad * 4 + r;
      if (gm >= Mrows) continue;
      int grow = crow_off + gm;
#pragma unroll
      for (int j = 0; j < 4; j++) {
        int gn = n0 + wn + j * 16 + frow;
        if (gn >= N) continue;
        float v = acc[i][j][r];
        if constexpr (BIAS) v += bias[gn];
        if constexpr (ACT == 1) v = v >= 0.f ? v : 0.2f * v;
        if constexpr (OSPLIT) {
          short h, l;
          split_bf16(v, h, l);
          Oh[(size_t)grow * N + gn] = h;
          Ol[(size_t)grow * N + gn] = l;
        } else {
          Co[(size_t)grow * ldc + gn] = v;
        }
      }
    }
  }
}

// ----------------------- split-bf16 MFMA GEMM (64x64) ----------------------
// OMODE: 0 fp32 Co (stride ldc), 1 hi/lo planes (stride ldo),
//        2 x_proj dual: planes (stride NDP) for gn<32 AND fp32
//          Co[row*32 + gn-24] for gn>=24 (B/C region).
// ACT: 0 none, 2 fast-softplus, 4 combine x = e2*(e1 + v) (stride ldc).
template <int ACT, bool BIAS, int OMODE>
__global__ __launch_bounds__(256) void mgemm64_k(
    const short* __restrict__ Ah, const short* __restrict__ Al, int lda, int K,
    const short* __restrict__ Wh, const short* __restrict__ Wl, int ldw, int N,
    const float* __restrict__ bias, float* __restrict__ Co, int ldc,
    short* __restrict__ Oh, short* __restrict__ Ol, int ldo,
    const float* __restrict__ e1, const float* __restrict__ e2, int Mrows,
    int crow_off) {
  __shared__ __align__(16) short sAh[64 * 32];
  __shared__ __align__(16) short sAl[64 * 32];
  __shared__ __align__(16) short sBh[64 * 32];
  __shared__ __align__(16) short sBl[64 * 32];
  const int tid = threadIdx.x;
  const int wave = tid >> 6, lane = tid & 63;
  const int m0 = blockIdx.y * 64, n0 = blockIdx.x * 64;
  const int srow = tid >> 2, schunk = tid & 3;  // 64 rows x 4 chunks of 16B
  const int frow = lane & 15, fquad = lane >> 4;

  int lm = m0 + srow;
  if (lm >= Mrows) lm = Mrows - 1;
  size_t aoff = (size_t)lm * lda;
  int wn_ = n0 + srow;
  if (wn_ >= N) wn_ = N - 1;
  size_t woff = (size_t)wn_ * ldw;

  floatx4 acc[4] = {};
  for (int k0 = 0; k0 < K; k0 += 32) {
    if (k0) __syncthreads();
    const int kc = k0 + schunk * 8;
    {
      short* lb = &sAh[(wave * 16) * 32];
      GLOAD_LDS16(Ah + aoff + kc, lb);
      lb = &sAl[(wave * 16) * 32];
      GLOAD_LDS16(Al + aoff + kc, lb);
      lb = &sBh[(wave * 16) * 32];
      GLOAD_LDS16(Wh + woff + kc, lb);
      lb = &sBl[(wave * 16) * 32];
      GLOAD_LDS16(Wl + woff + kc, lb);
    }
    __syncthreads();
    short8 ah[4], al[4], bh, bl;
#pragma unroll
    for (int i = 0; i < 4; i++) {
      int ra = (i * 16 + frow) * 32 + fquad * 8;
      ah[i] = *(const short8*)&sAh[ra];
      al[i] = *(const short8*)&sAl[ra];
    }
    {
      int rb = (wave * 16 + frow) * 32 + fquad * 8;
      bh = *(const short8*)&sBh[rb];
      bl = *(const short8*)&sBl[rb];
    }
#pragma unroll
    for (int i = 0; i < 4; i++) {
      acc[i] = __builtin_amdgcn_mfma_f32_16x16x32_bf16(ah[i], bh, acc[i], 0, 0, 0);
      acc[i] = __builtin_amdgcn_mfma_f32_16x16x32_bf16(al[i], bh, acc[i], 0, 0, 0);
      acc[i] = __builtin_amdgcn_mfma_f32_16x16x32_bf16(ah[i], bl, acc[i], 0, 0, 0);
    }
  }
  const int gn = n0 + wave * 16 + frow;
  if (gn < N) {
#pragma unroll
    for (int i = 0; i < 4; i++) {
#pragma unroll
      for (int r = 0; r < 4; r++) {
        int gm = m0 + i * 16 + fquad * 4 + r;
        if (gm >= Mrows) continue;
        int grow = crow_off + gm;
        float v = acc[i][r];
        if constexpr (BIAS) v += bias[gn];
        if constexpr (ACT == 2) v = (v > 20.f) ? v : __logf(1.f + __expf(v));
        if constexpr (ACT == 4) {
          size_t o = (size_t)grow * ldc + gn;
          v = e2[o] * (e1[o] + v);
        }
        if constexpr (OMODE == 1) {
          short h, l;
          split_bf16(v, h, l);
          Oh[(size_t)grow * ldo + gn] = h;
          Ol[(size_t)grow * ldo + gn] = l;
        } else if constexpr (OMODE == 2) {
          if (gn < NDP) {
            short h, l;
            split_bf16(v, h, l);
            Oh[(size_t)grow * NDP + gn] = h;
            Ol[(size_t)grow * NDP + gn] = l;
          }
          if (gn >= DTR) Co[(size_t)grow * 32 + (gn - DTR)] = v;
        } else {
          Co[(size_t)grow * ldc + gn] = v;
        }
      }
    }
  }
}

// --------------------------- depthwise conv + silu -------------------------
// 2 elements/thread; emits xc bf16 hi/lo planes.
__global__ __launch_bounds__(256) void conv_k(const float* __restrict__ xz,
                                              const float* __restrict__ cw,
                                              const float* __restrict__ cb,
                                              short* __restrict__ xch,
                                              short* __restrict__ xcl) {
  int idx = blockIdx.x * 256 + threadIdx.x;  // [0, MH*DI/2)
  int dh = idx % (DI / 2);
  int m = idx / (DI / 2);
  int d = dh * 2;
  int b = m / T, t = m - b * T;
  const float* base = xz + (size_t)b * T * XZdim + d;
  float a0 = cb[d], a1 = cb[d + 1];
#pragma unroll
  for (int j = 0; j < 4; j++) {
    int tt = t - 3 + j;
    if (tt >= 0) {
      float2 u = *(const float2*)(base + (size_t)tt * XZdim);
      a0 += u.x * cw[d * 4 + j];
      a1 += u.y * cw[(d + 1) * 4 + j];
    }
  }
  float v0 = a0 / (1.f + __expf(-a0));
  float v1 = a1 / (1.f + __expf(-a1));
  short h0, l0, h1, l1;
  split_bf16(v0, h0, l0);
  split_bf16(v1, h1, l1);
  size_t o = (size_t)m * DI + d;
  *(short2*)&xch[o] = make_short2(h0, h1);
  *(short2*)&xcl[o] = make_short2(l0, l1);
}

// ----------------------- chunked selective scan ----------------------------
// Phase 1: local scan from h=0; stores h_local[16] + sum(dt) per (b,ch,d).
// B from fp32 xdbc[row][0..15]; C at [16..31].
__global__ __launch_bounds__(256) void scan_p1_k(
    const float* __restrict__ xzb, const short* __restrict__ xch,
    const short* __restrict__ xcl, const float* __restrict__ xdbc,
    const float* __restrict__ alog, float* __restrict__ hchk,
    float* __restrict__ sdt) {
  int d = blockIdx.x * 256 + threadIdx.x;
  int ch = blockIdx.y, b = blockIdx.z;
  float A[DSTATE], h[DSTATE];
  bool powA = true;
#pragma unroll
  for (int s = 0; s < DSTATE; s++) {
    A[s] = -expf(alog[d * DSTATE + s]);
    powA = powA && (fabsf(A[s] + (float)(s + 1)) <= 1e-4f * (float)(s + 1));
    h[s] = 0.f;
  }
  const int t0 = ch * TC;
  const float* xzr = xzb + ((size_t)b * T + t0) * XZdim;
  const short* xchr = xch + ((size_t)b * T + t0) * DI;
  const short* xclr = xcl + ((size_t)b * T + t0) * DI;
  const float* bcr = xdbc + ((size_t)b * T + t0) * 32;
  float sd = 0.f;
  if (powA) {
    for (int t = 0; t < TC; t++) {
      float dt = xzr[(size_t)t * XZdim + d];
      float xv = join_bf16(xchr[(size_t)t * DI + d], xclr[(size_t)t * DI + d]);
      float dx = dt * xv;
      const float* bc = bcr + (size_t)t * 32;
      sd += dt;
      float ev[DSTATE];
      pow16(__expf(-dt), ev);
#pragma unroll
      for (int s = 0; s < DSTATE; s++) h[s] = h[s] * ev[s] + dx * bc[s];
    }
  } else {
    for (int t = 0; t < TC; t++) {
      float dt = xzr[(size_t)t * XZdim + d];
      float xv = join_bf16(xchr[(size_t)t * DI + d], xclr[(size_t)t * DI + d]);
      float dx = dt * xv;
      const float* bc = bcr + (size_t)t * 32;
      sd += dt;
#pragma unroll
      for (int s = 0; s < DSTATE; s++)
        h[s] = h[s] * __expf(dt * A[s]) + dx * bc[s];
    }
  }
  size_t o = ((size_t)(b * NCHUNK + ch) * DSTATE) * DI + d;
#pragma unroll
  for (int s = 0; s < DSTATE; s++) hchk[o + (size_t)s * DI] = h[s];
  sdt[(size_t)(b * NCHUNK + ch) * DI + d] = sd;
}

// Phase 2: per (b,s,d), 26-chunk recurrence; P recomputed from sdt.
__global__ __launch_bounds__(256) void scan_p2_k(float* __restrict__ hchk,
                                                 const float* __restrict__ sdt,
                                                 const float* __restrict__ alog) {
  int idx = blockIdx.x * 256 + threadIdx.x;  // [0, HB*DSTATE*DI)
  int d = idx % DI;
  int rem = idx / DI;
  int s = rem % DSTATE, b = rem / DSTATE;
  float A = -expf(alog[d * DSTATE + s]);
  float hin = 0.f;
#pragma unroll
  for (int ch = 0; ch < NCHUNK; ch++) {
    size_t o = ((size_t)(b * NCHUNK + ch) * DSTATE + s) * DI + d;
    float P = __expf(A * sdt[(size_t)(b * NCHUNK + ch) * DI + d]);
    float hl = hchk[o];
    hchk[o] = hin;
    hin = P * hin + hl;
  }
}

// Phase 3: rescan from incoming state; y = h.C + D*x, gated silu(z) -> planes.
__global__ __launch_bounds__(256) void scan_p3_k(
    const float* __restrict__ xzb, const short* __restrict__ xch,
    const short* __restrict__ xcl, const float* __restrict__ xdbc,
    const float* __restrict__ alog, const float* __restrict__ Dp,
    const float* __restrict__ hchk, short* __restrict__ yh,
    short* __restrict__ yl) {
  int d = blockIdx.x * 256 + threadIdx.x;
  int ch = blockIdx.y, b = blockIdx.z;
  float A[DSTATE], h[DSTATE];
  bool powA = true;
  size_t o = ((size_t)(b * NCHUNK + ch) * DSTATE) * DI + d;
#pragma unroll
  for (int s = 0; s < DSTATE; s++) {
    A[s] = -expf(alog[d * DSTATE + s]);
    powA = powA && (fabsf(A[s] + (float)(s + 1)) <= 1e-4f * (float)(s + 1));
    h[s] = hchk[o + (size_t)s * DI];
  }
  float Dd = Dp[d];
  const int t0 = ch * TC;
  const float* xzr = xzb + ((size_t)b * T + t0) * XZdim;
  const short* xchr = xch + ((size_t)b * T + t0) * DI;
  const short* xclr = xcl + ((size_t)b * T + t0) * DI;
  const float* bcr = xdbc + ((size_t)b * T + t0) * 32;
  if (powA) {
    for (int t = 0; t < TC; t++) {
      float dt = xzr[(size_t)t * XZdim + d];
      float xv = join_bf16(xchr[(size_t)t * DI + d], xclr[(size_t)t * DI + d]);
      float zv = xzr[(size_t)t * XZdim + DI + d];
      float dx = dt * xv;
      float accv = 0.f;
      const float* bc = bcr + (size_t)t * 32;
      float ev[DSTATE];
      pow16(__expf(-dt), ev);
#pragma unroll
      for (int s = 0; s < DSTATE; s++) {
        h[s] = h[s] * ev[s] + dx * bc[s];
        accv += h[s] * bc[DSTATE + s];
      }
      float y = accv + Dd * xv;
      float sz = zv / (1.f + __expf(-zv));
      float v = y * sz;
      short hh, ll;
      split_bf16(v, hh, ll);
      size_t oi = ((size_t)(b * T + t0 + t)) * DI + d;
      yh[oi] = hh;
      yl[oi] = ll;
    }
  } else {
    for (int t = 0; t < TC; t++) {
      float dt = xzr[(size_t)t * XZdim + d];
      float xv = join_bf16(xchr[(size_t)t * DI + d], xclr[(size_t)t * DI + d]);
      float zv = xzr[(size_t)t * XZdim + DI + d];
      float dx = dt * xv;
      float accv = 0.f;
      const float* bc = bcr + (size_t)t * 32;
#pragma unroll
      for (int s = 0; s < DSTATE; s++) {
        h[s] = h[s] * __expf(dt * A[s]) + dx * bc[s];
        accv += h[s] * bc[DSTATE + s];
      }
      float y = accv + Dd * xv;
      float sz = zv / (1.f + __expf(-zv));
      float v = y * sz;
      short hh, ll;
      split_bf16(v, hh, ll);
      size_t oi = ((size_t)(b * T + t0 + t)) * DI + d;
      yh[oi] = hh;
      yl[oi] = ll;
    }
  }
}

// --------------------------- final LN + scatter ----------------------------
__device__ __forceinline__ size_t out_index(int b, int t, int c) {
  if (t < NTOK) {
    int g_ = t >> 6, p = t & 63;
    int sec = g_ / 5, s = g_ % 5;
    return (size_t)sec * SEC_SZ + (((size_t)(b * 5 + s) * C + c) << 6) + p;
  }
  return 3 * SEC_SZ + ((size_t)b * 2 + (t - NTOK)) * C + c;
}

__global__ __launch_bounds__(128) void ln_scatter_k(const float* __restrict__ x,
                                                    const float* __restrict__ g,
                                                    const float* __restrict__ bb,
                                                    float* __restrict__ out) {
  int m = blockIdx.x, tid = threadIdx.x;
  int b = m / T, t = m - b * T;
  const float* xr = x + (size_t)m * C;
  float v0 = xr[tid], v1 = xr[tid + 128], v2 = xr[tid + 256];
  __shared__ float sm2[2];
  int wid = tid >> 6, lane = tid & 63;
  float s = v0 + v1 + v2;
#pragma unroll
  for (int o = 32; o > 0; o >>= 1) s += __shfl_xor(s, o, 64);
  if (lane == 0) sm2[wid] = s;
  __syncthreads();
  float mean = (sm2[0] + sm2[1]) * (1.f / 384.f);
  __syncthreads();
  float d0 = v0 - mean, d1 = v1 - mean, d2 = v2 - mean;
  float q = d0 * d0 + d1 * d1 + d2 * d2;
#pragma unroll
  for (int o = 32; o > 0; o >>= 1) q += __shfl_xor(q, o, 64);
  if (lane == 0) sm2[wid] = q;
  __syncthreads();
  float rstd = rsqrtf((sm2[0] + sm2[1]) * (1.f / 384.f) + 1e-5f);
  float vv[3] = {v0, v1, v2};
#pragma unroll
  for (int j = 0; j < 3; j++) {
    int c = tid + j * 128;
    out[out_index(b, t, c)] = (vv[j] - mean) * rstd * g[c] + bb[c];
  }
}

// --------------------------------- launch ----------------------------------
extern "C" void kernel_launch(void* const* d_in, const int* in_sizes, int n_in,
                              void* d_out, int out_size, void* d_ws,
                              size_t ws_size, hipStream_t stream) {
  const float* image = (const float*)d_in[0];
  const float* lidar = (const float*)d_in[1];
  const float* radar = (const float*)d_in[2];
  const float* gps = (const float*)d_in[3];
  const float* pe = (const float*)d_in[4];
  const float* ln1g = (const float*)d_in[5];
  const float* ln1b = (const float*)d_in[6];
  const float* fc1w = (const float*)d_in[7];
  const float* fc1b = (const float*)d_in[8];
  const float* fc2w = (const float*)d_in[9];
  const float* fc2b_ = (const float*)d_in[10];
  const float* inw = (const float*)d_in[11];
  const float* cw = (const float*)d_in[12];
  const float* cb = (const float*)d_in[13];
  const float* xw = (const float*)d_in[14];
  const float* dtw = (const float*)d_in[15];
  const float* dtb = (const float*)d_in[16];
  const float* alog = (const float*)d_in[17];
  const float* Dp = (const float*)d_in[18];
  const float* ow = (const float*)d_in[19];
  const float* lnfg = (const float*)d_in[20];
  const float* lnfb = (const float*)d_in[21];
  float* out = (float*)d_out;

  // ---------------- workspace carve-up (59,290,624 floats = 237.2 MB) ------
  constexpr size_t MC = (size_t)M * C;  // 5,910,528
  float* ws = (float*)d_ws;
  float* x = ws;                            // MC
  float* fcb = x + MC;                      // MC (fc2 lrelu result)
  float* bmfm = fcb + MC;                   // MC (ln planes alias; then bm)
  float* x1f = bmfm + MC;                   // MC (x1 planes)
  float* yf = x1f + MC;                     // MC (y planes, half-local)
  float* xz_h = yf + MC;                    // MH*1536
  float* xcp = xz_h + (size_t)MH * XZdim;   // MH*DI floats (xc planes)
  float* xdp = xcp + (size_t)MH * DI;       // MH*64 floats (dt planes + B/C)
  constexpr size_t CHK_H = (size_t)HB * NCHUNK * DSTATE * DI;  // 2,555,904
  float* hchk = xdp + (size_t)MH * 64;
  float* sdtb = hchk + CHK_H;               // HB*NCHUNK*DI = 159,744
  float* wpl = sdtb + (size_t)HB * NCHUNK * DI;

  short* lnh = (short*)bmfm;  // ln planes dead before bm written
  short* lnl = lnh + MC;
  float* bm = bmfm;  // dir1 out_proj result (fp32, full M)
  short* x1h = (short*)x1f;
  short* x1l = x1h + MC;
  short* yh = (short*)yf;
  short* yl = yh + (size_t)MH * DI;
  short* xch = (short*)xcp;
  short* xcl = xch + (size_t)MH * DI;
  short* xdh = (short*)xdp;                  // MH*32 shorts (dt_r hi plane)
  short* xdl = xdh + (size_t)MH * NDP;       // MH*32 shorts (dt_r lo plane)
  float* xdbc = xdp + (size_t)MH * 32;       // MH*32 floats (fp32 B|C) - FIXED

  constexpr size_t WSZ1 = (size_t)NLAYER * C * C;           // 589,824
  constexpr size_t WSZI = (size_t)NLAYER * 2 * 2 * DI * C;  // 4,718,592
  constexpr size_t WSZO = (size_t)NLAYER * 2 * C * DI;      // 2,359,296
  constexpr size_t WSZX = (size_t)NLAYER * 2 * ND * DI;     // 344,064
  constexpr size_t WSZD = (size_t)NLAYER * 2 * DI * 32;     // 196,608 (padded)
  short* wf1h = (short*)wpl;
  short* wf1l = wf1h + WSZ1;
  short* wf2h = wf1l + WSZ1;
  short* wf2l = wf2h + WSZ1;
  short* winh = wf2l + WSZ1;
  short* winl = winh + WSZI;
  short* wowh = winl + WSZI;
  short* wowl = wowh + WSZO;
  short* wxh = wowl + WSZO;
  short* wxl = wxh + WSZX;
  short* wdth = wxl + WSZX;
  short* wdtl = wdth + WSZD;

  // ---------------- weight plane casts (once per call) ----------------
  cast_k<<<(int)(WSZ1 / 256), 256, 0, stream>>>(fc1w, (int)WSZ1, wf1h, wf1l);
  cast_k<<<(int)(WSZ1 / 256), 256, 0, stream>>>(fc2w, (int)WSZ1, wf2h, wf2l);
  cast_k<<<(int)(WSZI / 256), 256, 0, stream>>>(inw, (int)WSZI, winh, winl);
  cast_k<<<(int)(WSZO / 256), 256, 0, stream>>>(ow, (int)WSZO, wowh, wowl);
  cast_k<<<(int)(WSZX / 256), 256, 0, stream>>>(xw, (int)WSZX, wxh, wxl);
  cast_pad_k<<<(int)(WSZD / 256), 256, 0, stream>>>(dtw, (int)WSZD, wdth, wdtl);

  assemble_k<<<(M * C) / 256, 256, 0, stream>>>(image, lidar, radar, gps, pe, x);

  for (int l = 0; l < NLAYER; l++) {
    ln_fused_k<<<M / 4, 256, 0, stream>>>(x, ln1g + l * C, ln1b + l * C, lnh,
                                          lnl);
    // fc1 = LN(x) @ fc1_w^T + b -> bf16 planes (full M)
    mgemm_k<0, true, false, true><<<dim3(3, 121), 256, 0, stream>>>(
        lnh, lnl, C, wf1h + (size_t)l * C * C, wf1l + (size_t)l * C * C, C,
        fc1b + l * C, nullptr, 0, x1h, x1l, M, 0, 0);
    // fcb = lrelu(flip(xfc1) @ fc2_w^T + b) -> fp32 (full M)
    mgemm_k<1, true, true, false><<<dim3(3, 121), 256, 0, stream>>>(
        x1h, x1l, C, wf2h + (size_t)l * C * C, wf2l + (size_t)l * C * C, C,
        fc2b_ + l * C, fcb, C, nullptr, nullptr, M, 0, 0);
    // dir1 (backward) first -> bm; dir0 last fuses combine into x.
    for (int di = 0; di < 2; di++) {
      const int dir = 1 - di;
      size_t wo = (size_t)(l * 2 + dir);
      for (int h = 0; h < 2; h++) {
        const int roff = h * MH;
        // in_proj -> xz_h (dir1 reads time-flipped rows of x1)
        if (dir == 0)
          mgemm_k<0, false, false, false><<<dim3(12, 61), 256, 0, stream>>>(
              x1h, x1l, C, winh + wo * 2 * DI * C, winl + wo * 2 * DI * C,
              2 * DI, nullptr, xz_h, XZdim, nullptr, nullptr, MH, roff, 0);
        else
          mgemm_k<0, false, true, false><<<dim3(12, 61), 256, 0, stream>>>(
              x1h, x1l, C, winh + wo * 2 * DI * C, winl + wo * 2 * DI * C,
              2 * DI, nullptr, xz_h, XZdim, nullptr, nullptr, MH, roff, 0);
        // causal depthwise conv + silu -> xc planes
        conv_k<<<(MH * DI / 2) / 256, 256, 0, stream>>>(
            xz_h, cw + wo * DI * DCONV, cb + wo * DI, xch, xcl);
        // x_proj -> dt_r planes (stride 32) + fp32 B/C (xdbc)
        mgemm64_k<0, false, 2><<<dim3(1, 121), 256, 0, stream>>>(
            xch, xcl, DI, DI, wxh + wo * ND * DI, wxl + wo * ND * DI, DI, ND,
            nullptr, xdbc, 0, xdh, xdl, NDP, nullptr, nullptr, MH, 0);
        // dt_proj (K padded 24->32, zero weight pad) + fast softplus -> xz dt
        mgemm64_k<2, true, 0><<<dim3(12, 121), 256, 0, stream>>>(
            xdh, xdl, NDP, 32, wdth + wo * DI * 32, wdtl + wo * DI * 32, 32,
            DI, dtb + wo * DI, xz_h, XZdim, nullptr, nullptr, 0, nullptr,
            nullptr, MH, 0);
        // chunked selective scan -> y planes
        scan_p1_k<<<dim3(3, NCHUNK, HB), 256, 0, stream>>>(
            xz_h, xch, xcl, xdbc, alog + wo * DI * DSTATE, hchk, sdtb);
        scan_p2_k<<<(HB * DSTATE * DI) / 256, 256, 0, stream>>>(
            hchk, sdtb, alog + wo * DI * DSTATE);
        scan_p3_k<<<dim3(3, NCHUNK, HB), 256, 0, stream>>>(
            xz_h, xch, xcl, xdbc, alog + wo * DI * DSTATE, Dp + wo * DI, hchk,
            yh, yl);
        // out_proj: dir1 -> bm (plain); dir0 -> x = bm*(fcb + v)
        if (dir == 1)
          mgemm64_k<0, false, 0><<<dim3(6, 121), 256, 0, stream>>>(
              yh, yl, DI, DI, wowh + wo * C * DI, wowl + wo * C * DI, DI, C,
              nullptr, bm, C, nullptr, nullptr, 0, nullptr, nullptr, MH, roff);
        else
          mgemm64_k<4, false, 0><<<dim3(6, 121), 256, 0, stream>>>(
              yh, yl, DI, DI, wowh + wo * C * DI, wowl + wo * C * DI, DI, C,
              nullptr, x, C, nullptr, nullptr, 0, fcb, bm, MH, roff);
      }
    }
  }
  ln_scatter_k<<<M, 128, 0, stream>>>(x, lnfg, lnfb, out);
}

// Round 9
// 3122.986 us; speedup vs baseline: 1.7106x; 1.1914x over previous
//
#include <hip/hip_runtime.h>
#include <cstdint>
#include <cstddef>

// ---------------------------------------------------------------------------
// MambaFusion. R8 (on R7):
// - conv_k: 4-t sliding-window quad (7 row-loads -> 4 outputs in registers);
//   VMEM/output 4 -> 1.75, grid 2892 blocks.
// - final LN: stats pass (aliases dead hchk) + LDS-transpose scatter kernel
//   with fully contiguous writes (was 9x write-amplified).
// Workspace: 59,290,624 floats = 237.2 MB (unchanged).
// ---------------------------------------------------------------------------

constexpr int BZv = 16, SEQ = 5, NV = 1;
constexpr int C = 384, DSTATE = 16, DCONV = 4, NLAYER = 4;
constexpr int DI = 768;
constexpr int DTR = 24;
constexpr int NTOK = (NV + 2) * SEQ * 64;  // 960
constexpr int T = NTOK + 2;                // 962
constexpr int M = BZv * T;                 // 15392
constexpr int HB = 8;                      // batches per half
constexpr int MH = HB * T;                 // 7696 rows per half
constexpr int XZdim = 2 * DI;              // 1536
constexpr int ND = DTR + 2 * DSTATE;       // 56
constexpr int NDP = 32;                    // dt_r plane stride
constexpr int NCHUNK = 26, TC = 37;        // 26*37 == 962
constexpr int NQ = 241;                    // ceil(T/4) t-quads
constexpr size_t SEC_SZ = (size_t)BZv * SEQ * C * 64;

typedef __attribute__((ext_vector_type(8))) short short8;
typedef __attribute__((ext_vector_type(4))) float floatx4;

#define GLOAD_LDS16(g, l)                                        \
  __builtin_amdgcn_global_load_lds(                              \
      (const __attribute__((address_space(1))) void*)(g),        \
      (__attribute__((address_space(3))) void*)(l), 16, 0, 0)

__device__ __forceinline__ void split_bf16(float v, short& hi, short& lo) {
  unsigned u = __float_as_uint(v);
  unsigned hib = u & 0xFFFF0000u;      // truncate to bf16
  float r = v - __uint_as_float(hib);  // exact residual
  hi = (short)(hib >> 16);
  lo = (short)(__float_as_uint(r) >> 16);
}

__device__ __forceinline__ float join_bf16(short h, short l) {
  return __uint_as_float((unsigned)(unsigned short)h << 16) +
         __uint_as_float((unsigned)(unsigned short)l << 16);
}

// e[s] = e1^(s+1), 15 muls, ~4 deep.
__device__ __forceinline__ void pow16(float e1, float* e) {
  e[0] = e1;
  e[1] = e1 * e1;
  e[3] = e[1] * e[1];
  e[7] = e[3] * e[3];
  e[15] = e[7] * e[7];
  e[2] = e[1] * e[0];
  e[4] = e[3] * e[0];
  e[5] = e[3] * e[1];
  e[6] = e[5] * e[0];
  e[8] = e[7] * e[0];
  e[9] = e[7] * e[1];
  e[10] = e[9] * e[0];
  e[11] = e[7] * e[3];
  e[12] = e[11] * e[0];
  e[13] = e[11] * e[1];
  e[14] = e[13] * e[0];
}

// ------------------------------ token assembly -----------------------------
__global__ __launch_bounds__(256) void assemble_k(
    const float* __restrict__ img, const float* __restrict__ lid,
    const float* __restrict__ rad, const float* __restrict__ gps,
    const float* __restrict__ pe, float* __restrict__ x) {
  int idx = blockIdx.x * 256 + threadIdx.x;
  int c = idx % C;
  int m = idx / C;
  int b = m / T, t = m - b * T;
  float v;
  if (t < NTOK) {
    int g_ = t >> 6, p = t & 63;
    int sec = g_ / 5, s = g_ % 5;
    int band = (c < 128) ? 0 : (c < 256 ? 1 : 2);
    int which = (band + sec) % 3;
    const float* src = (which == 0) ? img : (which == 1 ? lid : rad);
    v = src[(((size_t)(b * 5 + s) * C + c) << 6) + p];
  } else {
    v = gps[((size_t)b * 2 + (t - NTOK)) * C + c];
  }
  x[idx] = v + pe[(size_t)t * C + c];
}

// -------------------- fused LN (stats + apply -> planes) -------------------
__global__ __launch_bounds__(256) void ln_fused_k(
    const float* __restrict__ x, const float* __restrict__ g,
    const float* __restrict__ b, short* __restrict__ oh,
    short* __restrict__ ol) {
  int row = blockIdx.x * 4 + (threadIdx.x >> 6);
  int lane = threadIdx.x & 63;
  const float* xr = x + (size_t)row * C;
  float v[6];
  float s = 0.f;
#pragma unroll
  for (int j = 0; j < 6; j++) {
    v[j] = xr[lane + 64 * j];
    s += v[j];
  }
#pragma unroll
  for (int o = 32; o > 0; o >>= 1) s += __shfl_xor(s, o, 64);
  float mean = s * (1.f / 384.f);
  float q = 0.f;
#pragma unroll
  for (int j = 0; j < 6; j++) {
    float d = v[j] - mean;
    q += d * d;
  }
#pragma unroll
  for (int o = 32; o > 0; o >>= 1) q += __shfl_xor(q, o, 64);
  float rstd = rsqrtf(q * (1.f / 384.f) + 1e-5f);
#pragma unroll
  for (int j = 0; j < 6; j++) {
    int c = lane + 64 * j;
    float val = (v[j] - mean) * rstd * g[c] + b[c];
    short h, l;
    split_bf16(val, h, l);
    oh[(size_t)row * C + c] = h;
    ol[(size_t)row * C + c] = l;
  }
}

// ------------------------- LN row stats (final LN) -------------------------
__global__ __launch_bounds__(256) void ln_stats2_k(const float* __restrict__ x,
                                                   float* __restrict__ stats) {
  int row = blockIdx.x * 4 + (threadIdx.x >> 6);
  int lane = threadIdx.x & 63;
  const float* xr = x + (size_t)row * C;
  float v[6];
  float s = 0.f;
#pragma unroll
  for (int j = 0; j < 6; j++) {
    v[j] = xr[lane + 64 * j];
    s += v[j];
  }
#pragma unroll
  for (int o = 32; o > 0; o >>= 1) s += __shfl_xor(s, o, 64);
  float mean = s * (1.f / 384.f);
  float q = 0.f;
#pragma unroll
  for (int j = 0; j < 6; j++) {
    float d = v[j] - mean;
    q += d * d;
  }
#pragma unroll
  for (int o = 32; o > 0; o >>= 1) q += __shfl_xor(q, o, 64);
  if (lane == 0) {
    stats[2 * row] = mean;
    stats[2 * row + 1] = rsqrtf(q * (1.f / 384.f) + 1e-5f);
  }
}

// ------------------------ fp32 -> hi/lo plane casts ------------------------
__global__ __launch_bounds__(256) void cast_k(const float* __restrict__ src,
                                              int n, short* __restrict__ oh,
                                              short* __restrict__ ol) {
  int idx = blockIdx.x * 256 + threadIdx.x;
  if (idx >= n) return;
  short h, l;
  split_bf16(src[idx], h, l);
  oh[idx] = h;
  ol[idx] = l;
}

// dtw: [rows][24] -> planes [rows][32], zero-padded cols 24..31.
__global__ __launch_bounds__(256) void cast_pad_k(const float* __restrict__ src,
                                                  int n, short* __restrict__ oh,
                                                  short* __restrict__ ol) {
  int idx = blockIdx.x * 256 + threadIdx.x;
  if (idx >= n) return;
  int col = idx & 31, row = idx >> 5;
  float v = (col < DTR) ? src[row * DTR + col] : 0.f;
  short h, l;
  split_bf16(v, h, l);
  oh[idx] = h;
  ol[idx] = l;
}

// ----------------------- split-bf16 MFMA GEMM (128x128) --------------------
// ACT: 0 none, 1 lrelu(0.2). OSPLIT: write hi/lo planes (stride N).
template <int ACT, bool BIAS, bool FLIPA, bool OSPLIT>
__global__ __launch_bounds__(256) void mgemm_k(
    const short* __restrict__ Ah, const short* __restrict__ Al, int K,
    const short* __restrict__ Wh, const short* __restrict__ Wl, int N,
    const float* __restrict__ bias, float* __restrict__ Co, int ldc,
    short* __restrict__ Oh, short* __restrict__ Ol, int Mrows, int arow_off,
    int crow_off) {
  __shared__ __align__(16) short sAh[128 * 32];
  __shared__ __align__(16) short sAl[128 * 32];
  __shared__ __align__(16) short sBh[128 * 32];
  __shared__ __align__(16) short sBl[128 * 32];
  const int tid = threadIdx.x;
  const int wave = tid >> 6, lane = tid & 63;
  const int m0 = blockIdx.y * 128, n0 = blockIdx.x * 128;
  const int lrow = lane >> 2, lchunk = lane & 3;
  const int wm = (wave >> 1) * 64, wn = (wave & 1) * 64;
  const int frow = lane & 15, fquad = lane >> 4;

  size_t arow[2], wrow[2];
#pragma unroll
  for (int p = 0; p < 2; p++) {
    int r = p * 64 + wave * 16 + lrow;
    int lm = m0 + r;
    if (lm >= Mrows) lm = Mrows - 1;
    int g = arow_off + lm;
    if (FLIPA) {
      int bb = g / T;
      int tt = g - bb * T;
      g = bb * T + (T - 1 - tt);
    }
    arow[p] = (size_t)g * K;
    int gn = n0 + r;
    int sn = gn < N ? gn : N - 1;
    wrow[p] = (size_t)sn * K;
  }

  floatx4 acc[4][4] = {};
  for (int k0 = 0; k0 < K; k0 += 32) {
    if (k0) __syncthreads();
    const int kc = k0 + lchunk * 8;
#pragma unroll
    for (int p = 0; p < 2; p++) {
      short* lb = &sAh[(p * 64 + wave * 16) * 32];
      GLOAD_LDS16(Ah + arow[p] + kc, lb);
      lb = &sAl[(p * 64 + wave * 16) * 32];
      GLOAD_LDS16(Al + arow[p] + kc, lb);
      lb = &sBh[(p * 64 + wave * 16) * 32];
      GLOAD_LDS16(Wh + wrow[p] + kc, lb);
      lb = &sBl[(p * 64 + wave * 16) * 32];
      GLOAD_LDS16(Wl + wrow[p] + kc, lb);
    }
    __syncthreads();
    short8 ah[4], al[4], bh[4], bl[4];
#pragma unroll
    for (int i = 0; i < 4; i++) {
      int ra = (wm + i * 16 + frow) * 32 + fquad * 8;
      int rb = (wn + i * 16 + frow) * 32 + fquad * 8;
      ah[i] = *(const short8*)&sAh[ra];
      al[i] = *(const short8*)&sAl[ra];
      bh[i] = *(const short8*)&sBh[rb];
      bl[i] = *(const short8*)&sBl[rb];
    }
#pragma unroll
    for (int i = 0; i < 4; i++)
#pragma unroll
      for (int j = 0; j < 4; j++) {
        acc[i][j] = __builtin_amdgcn_mfma_f32_16x16x32_bf16(ah[i], bh[j],
                                                            acc[i][j], 0, 0, 0);
        acc[i][j] = __builtin_amdgcn_mfma_f32_16x16x32_bf16(al[i], bh[j],
                                                            acc[i][j], 0, 0, 0);
        acc[i][j] = __builtin_amdgcn_mfma_f32_16x16x32_bf16(ah[i], bl[j],
                                                            acc[i][j], 0, 0, 0);
      }
  }
#pragma unroll
  for (int i = 0; i < 4; i++) {
#pragma unroll
    for (int r = 0; r < 4; r++) {
      int gm = m0 + wm + i * 16 + fquad * 4 + r;
      if (gm >= Mrows) continue;
      int grow = crow_off + gm;
#pragma unroll
      for (int j = 0; j < 4; j++) {
        int gn = n0 + wn + j * 16 + frow;
        if (gn >= N) continue;
        float v = acc[i][j][r];
        if constexpr (BIAS) v += bias[gn];
        if constexpr (ACT == 1) v = v >= 0.f ? v : 0.2f * v;
        if constexpr (OSPLIT) {
          short h, l;
          split_bf16(v, h, l);
          Oh[(size_t)grow * N + gn] = h;
          Ol[(size_t)grow * N + gn] = l;
        } else {
          Co[(size_t)grow * ldc + gn] = v;
        }
      }
    }
  }
}

// ----------------------- split-bf16 MFMA GEMM (64x64) ----------------------
// OMODE: 0 fp32 Co (stride ldc), 1 hi/lo planes (stride ldo),
//        2 x_proj dual: planes (stride NDP) for gn<32 AND fp32
//          Co[row*32 + gn-24] for gn>=24 (B/C region).
// ACT: 0 none, 2 fast-softplus, 4 combine x = e2*(e1 + v) (stride ldc).
template <int ACT, bool BIAS, int OMODE>
__global__ __launch_bounds__(256) void mgemm64_k(
    const short* __restrict__ Ah, const short* __restrict__ Al, int lda, int K,
    const short* __restrict__ Wh, const short* __restrict__ Wl, int ldw, int N,
    const float* __restrict__ bias, float* __restrict__ Co, int ldc,
    short* __restrict__ Oh, short* __restrict__ Ol, int ldo,
    const float* __restrict__ e1, const float* __restrict__ e2, int Mrows,
    int crow_off) {
  __shared__ __align__(16) short sAh[64 * 32];
  __shared__ __align__(16) short sAl[64 * 32];
  __shared__ __align__(16) short sBh[64 * 32];
  __shared__ __align__(16) short sBl[64 * 32];
  const int tid = threadIdx.x;
  const int wave = tid >> 6, lane = tid & 63;
  const int m0 = blockIdx.y * 64, n0 = blockIdx.x * 64;
  const int srow = tid >> 2, schunk = tid & 3;  // 64 rows x 4 chunks of 16B
  const int frow = lane & 15, fquad = lane >> 4;

  int lm = m0 + srow;
  if (lm >= Mrows) lm = Mrows - 1;
  size_t aoff = (size_t)lm * lda;
  int wn_ = n0 + srow;
  if (wn_ >= N) wn_ = N - 1;
  size_t woff = (size_t)wn_ * ldw;

  floatx4 acc[4] = {};
  for (int k0 = 0; k0 < K; k0 += 32) {
    if (k0) __syncthreads();
    const int kc = k0 + schunk * 8;
    {
      short* lb = &sAh[(wave * 16) * 32];
      GLOAD_LDS16(Ah + aoff + kc, lb);
      lb = &sAl[(wave * 16) * 32];
      GLOAD_LDS16(Al + aoff + kc, lb);
      lb = &sBh[(wave * 16) * 32];
      GLOAD_LDS16(Wh + woff + kc, lb);
      lb = &sBl[(wave * 16) * 32];
      GLOAD_LDS16(Wl + woff + kc, lb);
    }
    __syncthreads();
    short8 ah[4], al[4], bh, bl;
#pragma unroll
    for (int i = 0; i < 4; i++) {
      int ra = (i * 16 + frow) * 32 + fquad * 8;
      ah[i] = *(const short8*)&sAh[ra];
      al[i] = *(const short8*)&sAl[ra];
    }
    {
      int rb = (wave * 16 + frow) * 32 + fquad * 8;
      bh = *(const short8*)&sBh[rb];
      bl = *(const short8*)&sBl[rb];
    }
#pragma unroll
    for (int i = 0; i < 4; i++) {
      acc[i] = __builtin_amdgcn_mfma_f32_16x16x32_bf16(ah[i], bh, acc[i], 0, 0, 0);
      acc[i] = __builtin_amdgcn_mfma_f32_16x16x32_bf16(al[i], bh, acc[i], 0, 0, 0);
      acc[i] = __builtin_amdgcn_mfma_f32_16x16x32_bf16(ah[i], bl, acc[i], 0, 0, 0);
    }
  }
  const int gn = n0 + wave * 16 + frow;
  if (gn < N) {
#pragma unroll
    for (int i = 0; i < 4; i++) {
#pragma unroll
      for (int r = 0; r < 4; r++) {
        int gm = m0 + i * 16 + fquad * 4 + r;
        if (gm >= Mrows) continue;
        int grow = crow_off + gm;
        float v = acc[i][r];
        if constexpr (BIAS) v += bias[gn];
        if constexpr (ACT == 2) v = (v > 20.f) ? v : __logf(1.f + __expf(v));
        if constexpr (ACT == 4) {
          size_t o = (size_t)grow * ldc + gn;
          v = e2[o] * (e1[o] + v);
        }
        if constexpr (OMODE == 1) {
          short h, l;
          split_bf16(v, h, l);
          Oh[(size_t)grow * ldo + gn] = h;
          Ol[(size_t)grow * ldo + gn] = l;
        } else if constexpr (OMODE == 2) {
          if (gn < NDP) {
            short h, l;
            split_bf16(v, h, l);
            Oh[(size_t)grow * NDP + gn] = h;
            Ol[(size_t)grow * NDP + gn] = l;
          }
          if (gn >= DTR) Co[(size_t)grow * 32 + (gn - DTR)] = v;
        } else {
          Co[(size_t)grow * ldc + gn] = v;
        }
      }
    }
  }
}

// --------------------------- depthwise conv + silu -------------------------
// 4-t sliding-window quad: thread per (b, t-quad, d-pair); 7 row-loads ->
// 4 outputs from registers. Emits xc bf16 hi/lo planes.
__global__ __launch_bounds__(256) void conv_k(const float* __restrict__ xz,
                                              const float* __restrict__ cw,
                                              const float* __restrict__ cb,
                                              short* __restrict__ xch,
                                              short* __restrict__ xcl) {
  int idx = blockIdx.x * 256 + threadIdx.x;  // [0, HB*NQ*384)
  int dh = idx % (DI / 2);
  int rem = idx / (DI / 2);
  int q = rem % NQ;
  int b = rem / NQ;
  int d = dh * 2;
  int t0 = q * 4;
  const float* base = xz + (size_t)b * T * XZdim + d;
  float4 cwa = *(const float4*)&cw[d * 4];
  float4 cwb = *(const float4*)&cw[(d + 1) * 4];
  float cb0 = cb[d], cb1 = cb[d + 1];
  float2 w[7];
#pragma unroll
  for (int j = 0; j < 7; j++) {
    int tt = t0 - 3 + j;
    w[j] = (tt >= 0 && tt < T) ? *(const float2*)(base + (size_t)tt * XZdim)
                               : make_float2(0.f, 0.f);
  }
  const float cwx[4] = {cwa.x, cwa.y, cwa.z, cwa.w};
  const float cwy[4] = {cwb.x, cwb.y, cwb.z, cwb.w};
#pragma unroll
  for (int r = 0; r < 4; r++) {
    int t = t0 + r;
    if (t >= T) break;
    float a0 = cb0, a1 = cb1;
#pragma unroll
    for (int j = 0; j < 4; j++) {
      a0 += w[r + j].x * cwx[j];
      a1 += w[r + j].y * cwy[j];
    }
    float v0 = a0 / (1.f + __expf(-a0));
    float v1 = a1 / (1.f + __expf(-a1));
    short h0, l0, h1, l1;
    split_bf16(v0, h0, l0);
    split_bf16(v1, h1, l1);
    size_t o = ((size_t)b * T + t) * DI + d;
    *(short2*)&xch[o] = make_short2(h0, h1);
    *(short2*)&xcl[o] = make_short2(l0, l1);
  }
}

// ----------------------- chunked selective scan ----------------------------
// Phase 1: local scan from h=0; stores h_local[16] + sum(dt) per (b,ch,d).
// B from fp32 xdbc[row][0..15]; C at [16..31].
__global__ __launch_bounds__(256) void scan_p1_k(
    const float* __restrict__ xzb, const short* __restrict__ xch,
    const short* __restrict__ xcl, const float* __restrict__ xdbc,
    const float* __restrict__ alog, float* __restrict__ hchk,
    float* __restrict__ sdt) {
  int d = blockIdx.x * 256 + threadIdx.x;
  int ch = blockIdx.y, b = blockIdx.z;
  float A[DSTATE], h[DSTATE];
  bool powA = true;
#pragma unroll
  for (int s = 0; s < DSTATE; s++) {
    A[s] = -expf(alog[d * DSTATE + s]);
    powA = powA && (fabsf(A[s] + (float)(s + 1)) <= 1e-4f * (float)(s + 1));
    h[s] = 0.f;
  }
  const int t0 = ch * TC;
  const float* xzr = xzb + ((size_t)b * T + t0) * XZdim;
  const short* xchr = xch + ((size_t)b * T + t0) * DI;
  const short* xclr = xcl + ((size_t)b * T + t0) * DI;
  const float* bcr = xdbc + ((size_t)b * T + t0) * 32;
  float sd = 0.f;
  if (powA) {
    for (int t = 0; t < TC; t++) {
      float dt = xzr[(size_t)t * XZdim + d];
      float xv = join_bf16(xchr[(size_t)t * DI + d], xclr[(size_t)t * DI + d]);
      float dx = dt * xv;
      const float* bc = bcr + (size_t)t * 32;
      sd += dt;
      float ev[DSTATE];
      pow16(__expf(-dt), ev);
#pragma unroll
      for (int s = 0; s < DSTATE; s++) h[s] = h[s] * ev[s] + dx * bc[s];
    }
  } else {
    for (int t = 0; t < TC; t++) {
      float dt = xzr[(size_t)t * XZdim + d];
      float xv = join_bf16(xchr[(size_t)t * DI + d], xclr[(size_t)t * DI + d]);
      float dx = dt * xv;
      const float* bc = bcr + (size_t)t * 32;
      sd += dt;
#pragma unroll
      for (int s = 0; s < DSTATE; s++)
        h[s] = h[s] * __expf(dt * A[s]) + dx * bc[s];
    }
  }
  size_t o = ((size_t)(b * NCHUNK + ch) * DSTATE) * DI + d;
#pragma unroll
  for (int s = 0; s < DSTATE; s++) hchk[o + (size_t)s * DI] = h[s];
  sdt[(size_t)(b * NCHUNK + ch) * DI + d] = sd;
}

// Phase 2: per (b,s,d), 26-chunk recurrence; P recomputed from sdt.
__global__ __launch_bounds__(256) void scan_p2_k(float* __restrict__ hchk,
                                                 const float* __restrict__ sdt,
                                                 const float* __restrict__ alog) {
  int idx = blockIdx.x * 256 + threadIdx.x;  // [0, HB*DSTATE*DI)
  int d = idx % DI;
  int rem = idx / DI;
  int s = rem % DSTATE, b = rem / DSTATE;
  float A = -expf(alog[d * DSTATE + s]);
  float hin = 0.f;
#pragma unroll
  for (int ch = 0; ch < NCHUNK; ch++) {
    size_t o = ((size_t)(b * NCHUNK + ch) * DSTATE + s) * DI + d;
    float P = __expf(A * sdt[(size_t)(b * NCHUNK + ch) * DI + d]);
    float hl = hchk[o];
    hchk[o] = hin;
    hin = P * hin + hl;
  }
}

// Phase 3: rescan from incoming state; y = h.C + D*x, gated silu(z) -> planes.
__global__ __launch_bounds__(256) void scan_p3_k(
    const float* __restrict__ xzb, const short* __restrict__ xch,
    const short* __restrict__ xcl, const float* __restrict__ xdbc,
    const float* __restrict__ alog, const float* __restrict__ Dp,
    const float* __restrict__ hchk, short* __restrict__ yh,
    short* __restrict__ yl) {
  int d = blockIdx.x * 256 + threadIdx.x;
  int ch = blockIdx.y, b = blockIdx.z;
  float A[DSTATE], h[DSTATE];
  bool powA = true;
  size_t o = ((size_t)(b * NCHUNK + ch) * DSTATE) * DI + d;
#pragma unroll
  for (int s = 0; s < DSTATE; s++) {
    A[s] = -expf(alog[d * DSTATE + s]);
    powA = powA && (fabsf(A[s] + (float)(s + 1)) <= 1e-4f * (float)(s + 1));
    h[s] = hchk[o + (size_t)s * DI];
  }
  float Dd = Dp[d];
  const int t0 = ch * TC;
  const float* xzr = xzb + ((size_t)b * T + t0) * XZdim;
  const short* xchr = xch + ((size_t)b * T + t0) * DI;
  const short* xclr = xcl + ((size_t)b * T + t0) * DI;
  const float* bcr = xdbc + ((size_t)b * T + t0) * 32;
  if (powA) {
    for (int t = 0; t < TC; t++) {
      float dt = xzr[(size_t)t * XZdim + d];
      float xv = join_bf16(xchr[(size_t)t * DI + d], xclr[(size_t)t * DI + d]);
      float zv = xzr[(size_t)t * XZdim + DI + d];
      float dx = dt * xv;
      float accv = 0.f;
      const float* bc = bcr + (size_t)t * 32;
      float ev[DSTATE];
      pow16(__expf(-dt), ev);
#pragma unroll
      for (int s = 0; s < DSTATE; s++) {
        h[s] = h[s] * ev[s] + dx * bc[s];
        accv += h[s] * bc[DSTATE + s];
      }
      float y = accv + Dd * xv;
      float sz = zv / (1.f + __expf(-zv));
      float v = y * sz;
      short hh, ll;
      split_bf16(v, hh, ll);
      size_t oi = ((size_t)(b * T + t0 + t)) * DI + d;
      yh[oi] = hh;
      yl[oi] = ll;
    }
  } else {
    for (int t = 0; t < TC; t++) {
      float dt = xzr[(size_t)t * XZdim + d];
      float xv = join_bf16(xchr[(size_t)t * DI + d], xclr[(size_t)t * DI + d]);
      float zv = xzr[(size_t)t * XZdim + DI + d];
      float dx = dt * xv;
      float accv = 0.f;
      const float* bc = bcr + (size_t)t * 32;
#pragma unroll
      for (int s = 0; s < DSTATE; s++) {
        h[s] = h[s] * __expf(dt * A[s]) + dx * bc[s];
        accv += h[s] * bc[DSTATE + s];
      }
      float y = accv + Dd * xv;
      float sz = zv / (1.f + __expf(-zv));
      float v = y * sz;
      short hh, ll;
      split_bf16(v, hh, ll);
      size_t oi = ((size_t)(b * T + t0 + t)) * DI + d;
      yh[oi] = hh;
      yl[oi] = ll;
    }
  }
}

// ---------------- final LN + transpose scatter (contiguous writes) ---------
// Blocks 0..239: (b, g_) token-groups; LDS-transpose 64x128 tiles.
// Block 240: gps tail rows.
__global__ __launch_bounds__(256) void ln_scatter_k(
    const float* __restrict__ x, const float* __restrict__ stats,
    const float* __restrict__ g, const float* __restrict__ bb,
    float* __restrict__ out) {
  __shared__ float lds[64][129];
  int blk = blockIdx.x, tid = threadIdx.x;
  if (blk < 240) {
    int b = blk / 15, g_ = blk % 15;
    int sec = g_ / 5, s = g_ % 5;
    const int rbase = b * T + g_ * 64;
    for (int cc = 0; cc < 3; cc++) {
      if (cc) __syncthreads();
#pragma unroll
      for (int i = 0; i < 32; i++) {
        int lin = tid + 256 * i;  // [0, 8192)
        int p = lin >> 7, c = lin & 127;
        int row = rbase + p;
        int ccc = cc * 128 + c;
        float v = x[(size_t)row * C + ccc];
        v = (v - stats[2 * row]) * stats[2 * row + 1] * g[ccc] + bb[ccc];
        lds[p][c] = v;
      }
      __syncthreads();
      size_t obase = (size_t)sec * SEC_SZ +
                     (((size_t)(b * 5 + s) * C + cc * 128) << 6);
#pragma unroll
      for (int i = 0; i < 32; i++) {
        int lin = tid + 256 * i;
        int c = lin >> 6, p = lin & 63;
        out[obase + ((size_t)c << 6) + p] = lds[p][c];
      }
    }
  } else {
    // gps tails: 16 b x 2 rows x 384 c = 12288 elems
#pragma unroll
    for (int i = 0; i < 48; i++) {
      int lin = tid + 256 * i;
      int r = lin / C, c = lin % C;
      int b = r >> 1, e = r & 1;
      int row = b * T + NTOK + e;
      float v = x[(size_t)row * C + c];
      v = (v - stats[2 * row]) * stats[2 * row + 1] * g[c] + bb[c];
      out[3 * SEC_SZ + ((size_t)(b * 2 + e)) * C + c] = v;
    }
  }
}

// --------------------------------- launch ----------------------------------
extern "C" void kernel_launch(void* const* d_in, const int* in_sizes, int n_in,
                              void* d_out, int out_size, void* d_ws,
                              size_t ws_size, hipStream_t stream) {
  const float* image = (const float*)d_in[0];
  const float* lidar = (const float*)d_in[1];
  const float* radar = (const float*)d_in[2];
  const float* gps = (const float*)d_in[3];
  const float* pe = (const float*)d_in[4];
  const float* ln1g = (const float*)d_in[5];
  const float* ln1b = (const float*)d_in[6];
  const float* fc1w = (const float*)d_in[7];
  const float* fc1b = (const float*)d_in[8];
  const float* fc2w = (const float*)d_in[9];
  const float* fc2b_ = (const float*)d_in[10];
  const float* inw = (const float*)d_in[11];
  const float* cw = (const float*)d_in[12];
  const float* cb = (const float*)d_in[13];
  const float* xw = (const float*)d_in[14];
  const float* dtw = (const float*)d_in[15];
  const float* dtb = (const float*)d_in[16];
  const float* alog = (const float*)d_in[17];
  const float* Dp = (const float*)d_in[18];
  const float* ow = (const float*)d_in[19];
  const float* lnfg = (const float*)d_in[20];
  const float* lnfb = (const float*)d_in[21];
  float* out = (float*)d_out;

  // ---------------- workspace carve-up (59,290,624 floats = 237.2 MB) ------
  constexpr size_t MC = (size_t)M * C;  // 5,910,528
  float* ws = (float*)d_ws;
  float* x = ws;                            // MC
  float* fcb = x + MC;                      // MC (fc2 lrelu result)
  float* bmfm = fcb + MC;                   // MC (ln planes alias; then bm)
  float* x1f = bmfm + MC;                   // MC (x1 planes)
  float* yf = x1f + MC;                     // MC (y planes, half-local)
  float* xz_h = yf + MC;                    // MH*1536
  float* xcp = xz_h + (size_t)MH * XZdim;   // MH*DI floats (xc planes)
  float* xdp = xcp + (size_t)MH * DI;       // MH*64 floats (dt planes + B/C)
  constexpr size_t CHK_H = (size_t)HB * NCHUNK * DSTATE * DI;  // 2,555,904
  float* hchk = xdp + (size_t)MH * 64;
  float* sdtb = hchk + CHK_H;               // HB*NCHUNK*DI = 159,744
  float* wpl = sdtb + (size_t)HB * NCHUNK * DI;
  float* stats2 = hchk;  // final-LN stats alias (hchk dead by then)

  short* lnh = (short*)bmfm;  // ln planes dead before bm written
  short* lnl = lnh + MC;
  float* bm = bmfm;  // dir1 out_proj result (fp32, full M)
  short* x1h = (short*)x1f;
  short* x1l = x1h + MC;
  short* yh = (short*)yf;
  short* yl = yh + (size_t)MH * DI;
  short* xch = (short*)xcp;
  short* xcl = xch + (size_t)MH * DI;
  short* xdh = (short*)xdp;                  // MH*32 shorts (dt_r hi plane)
  short* xdl = xdh + (size_t)MH * NDP;       // MH*32 shorts (dt_r lo plane)
  float* xdbc = xdp + (size_t)MH * 32;       // MH*32 floats (fp32 B|C)

  constexpr size_t WSZ1 = (size_t)NLAYER * C * C;           // 589,824
  constexpr size_t WSZI = (size_t)NLAYER * 2 * 2 * DI * C;  // 4,718,592
  constexpr size_t WSZO = (size_t)NLAYER * 2 * C * DI;      // 2,359,296
  constexpr size_t WSZX = (size_t)NLAYER * 2 * ND * DI;     // 344,064
  constexpr size_t WSZD = (size_t)NLAYER * 2 * DI * 32;     // 196,608 (padded)
  short* wf1h = (short*)wpl;
  short* wf1l = wf1h + WSZ1;
  short* wf2h = wf1l + WSZ1;
  short* wf2l = wf2h + WSZ1;
  short* winh = wf2l + WSZ1;
  short* winl = winh + WSZI;
  short* wowh = winl + WSZI;
  short* wowl = wowh + WSZO;
  short* wxh = wowl + WSZO;
  short* wxl = wxh + WSZX;
  short* wdth = wxl + WSZX;
  short* wdtl = wdth + WSZD;

  // ---------------- weight plane casts (once per call) ----------------
  cast_k<<<(int)(WSZ1 / 256), 256, 0, stream>>>(fc1w, (int)WSZ1, wf1h, wf1l);
  cast_k<<<(int)(WSZ1 / 256), 256, 0, stream>>>(fc2w, (int)WSZ1, wf2h, wf2l);
  cast_k<<<(int)(WSZI / 256), 256, 0, stream>>>(inw, (int)WSZI, winh, winl);
  cast_k<<<(int)(WSZO / 256), 256, 0, stream>>>(ow, (int)WSZO, wowh, wowl);
  cast_k<<<(int)(WSZX / 256), 256, 0, stream>>>(xw, (int)WSZX, wxh, wxl);
  cast_pad_k<<<(int)(WSZD / 256), 256, 0, stream>>>(dtw, (int)WSZD, wdth, wdtl);

  assemble_k<<<(M * C) / 256, 256, 0, stream>>>(image, lidar, radar, gps, pe, x);

  for (int l = 0; l < NLAYER; l++) {
    ln_fused_k<<<M / 4, 256, 0, stream>>>(x, ln1g + l * C, ln1b + l * C, lnh,
                                          lnl);
    // fc1 = LN(x) @ fc1_w^T + b -> bf16 planes (full M)
    mgemm_k<0, true, false, true><<<dim3(3, 121), 256, 0, stream>>>(
        lnh, lnl, C, wf1h + (size_t)l * C * C, wf1l + (size_t)l * C * C, C,
        fc1b + l * C, nullptr, 0, x1h, x1l, M, 0, 0);
    // fcb = lrelu(flip(xfc1) @ fc2_w^T + b) -> fp32 (full M)
    mgemm_k<1, true, true, false><<<dim3(3, 121), 256, 0, stream>>>(
        x1h, x1l, C, wf2h + (size_t)l * C * C, wf2l + (size_t)l * C * C, C,
        fc2b_ + l * C, fcb, C, nullptr, nullptr, M, 0, 0);
    // dir1 (backward) first -> bm; dir0 last fuses combine into x.
    for (int di = 0; di < 2; di++) {
      const int dir = 1 - di;
      size_t wo = (size_t)(l * 2 + dir);
      for (int h = 0; h < 2; h++) {
        const int roff = h * MH;
        // in_proj -> xz_h (dir1 reads time-flipped rows of x1)
        if (dir == 0)
          mgemm_k<0, false, false, false><<<dim3(12, 61), 256, 0, stream>>>(
              x1h, x1l, C, winh + wo * 2 * DI * C, winl + wo * 2 * DI * C,
              2 * DI, nullptr, xz_h, XZdim, nullptr, nullptr, MH, roff, 0);
        else
          mgemm_k<0, false, true, false><<<dim3(12, 61), 256, 0, stream>>>(
              x1h, x1l, C, winh + wo * 2 * DI * C, winl + wo * 2 * DI * C,
              2 * DI, nullptr, xz_h, XZdim, nullptr, nullptr, MH, roff, 0);
        // causal depthwise conv + silu -> xc planes (4-t quad)
        conv_k<<<(HB * NQ * (DI / 2)) / 256, 256, 0, stream>>>(
            xz_h, cw + wo * DI * DCONV, cb + wo * DI, xch, xcl);
        // x_proj -> dt_r planes (stride 32) + fp32 B/C (xdbc)
        mgemm64_k<0, false, 2><<<dim3(1, 121), 256, 0, stream>>>(
            xch, xcl, DI, DI, wxh + wo * ND * DI, wxl + wo * ND * DI, DI, ND,
            nullptr, xdbc, 0, xdh, xdl, NDP, nullptr, nullptr, MH, 0);
        // dt_proj (K padded 24->32, zero weight pad) + fast softplus -> xz dt
        mgemm64_k<2, true, 0><<<dim3(12, 121), 256, 0, stream>>>(
            xdh, xdl, NDP, 32, wdth + wo * DI * 32, wdtl + wo * DI * 32, 32,
            DI, dtb + wo * DI, xz_h, XZdim, nullptr, nullptr, 0, nullptr,
            nullptr, MH, 0);
        // chunked selective scan -> y planes
        scan_p1_k<<<dim3(3, NCHUNK, HB), 256, 0, stream>>>(
            xz_h, xch, xcl, xdbc, alog + wo * DI * DSTATE, hchk, sdtb);
        scan_p2_k<<<(HB * DSTATE * DI) / 256, 256, 0, stream>>>(
            hchk, sdtb, alog + wo * DI * DSTATE);
        scan_p3_k<<<dim3(3, NCHUNK, HB), 256, 0, stream>>>(
            xz_h, xch, xcl, xdbc, alog + wo * DI * DSTATE, Dp + wo * DI, hchk,
            yh, yl);
        // out_proj: dir1 -> bm (plain); dir0 -> x = bm*(fcb + v)
        if (dir == 1)
          mgemm64_k<0, false, 0><<<dim3(6, 121), 256, 0, stream>>>(
              yh, yl, DI, DI, wowh + wo * C * DI, wowl + wo * C * DI, DI, C,
              nullptr, bm, C, nullptr, nullptr, 0, nullptr, nullptr, MH, roff);
        else
          mgemm64_k<4, false, 0><<<dim3(6, 121), 256, 0, stream>>>(
              yh, yl, DI, DI, wowh + wo * C * DI, wowl + wo * C * DI, DI, C,
              nullptr, x, C, nullptr, nullptr, 0, fcb, bm, MH, roff);
      }
    }
  }
  ln_stats2_k<<<M / 4, 256, 0, stream>>>(x, stats2);
  ln_scatter_k<<<241, 256, 0, stream>>>(x, stats2, lnfg, lnfb, out);
}